// Round 2
// baseline (510.906 us; speedup 1.0000x reference)
//
#include <hip/hip_runtime.h>
#include <stdint.h>

#define B_   16
#define N_   4096
#define M_   1024
#define C1_  256
#define C2_  512
#define H_   256
#define K1_  768      // C1+C2
#define P_   65536    // B*N

typedef unsigned int  uint_t;
typedef unsigned short ushort_t;
typedef __attribute__((ext_vector_type(4))) float f32x4;
typedef __attribute__((ext_vector_type(8))) short s16x8;

__device__ __forceinline__ float b2f(ushort_t u) {
    union { uint_t i; float f; } v; v.i = ((uint_t)u) << 16; return v.f;
}
__device__ __forceinline__ ushort_t f2b(float f) {
    union { float f; uint_t i; } v; v.f = f;
    uint_t x = v.i;
    return (ushort_t)((x + 0x7fffu + ((x >> 16) & 1u)) >> 16);  // RNE
}

__device__ __forceinline__ void async16(const void* g, void* l) {
    __builtin_amdgcn_global_load_lds(
        (const __attribute__((address_space(1))) uint_t*)g,
        (__attribute__((address_space(3))) uint_t*)l, 16, 0, 0);
}

// ---------------------------------------------------------------------------
// Zero the stats scratch (2048 floats).
// ---------------------------------------------------------------------------
__global__ __launch_bounds__(256) void zero_k(float* __restrict__ p) {
    p[blockIdx.x * 256 + threadIdx.x] = 0.0f;
}

// ---------------------------------------------------------------------------
// Convert w1 (256x768 f32) and w2 (256x256 f32) to bf16.
// ---------------------------------------------------------------------------
__global__ __launch_bounds__(256) void cvtw_k(
    const float* __restrict__ w1, const float* __restrict__ w2,
    ushort_t* __restrict__ w1b, ushort_t* __restrict__ w2b) {
    int t = blockIdx.x * 256 + threadIdx.x;   // 262144 total
    if (t < H_ * K1_) w1b[t] = f2b(w1[t]);
    else { int u = t - H_ * K1_; w2b[u] = f2b(w2[u]); }
}

// ---------------------------------------------------------------------------
// known_feats (B, 512, 1024) f32 -> kfT (B, 1024, 512) bf16, 64x64 LDS tiles
// ---------------------------------------------------------------------------
__global__ __launch_bounds__(256) void tkf_k(
    const float* __restrict__ in, ushort_t* __restrict__ out) {
    __shared__ ushort_t tile[64][65];
    int m0 = blockIdx.x * 64, c0 = blockIdx.y * 64, b = blockIdx.z;
    int t = threadIdx.x;
    {
        int ml = t & 63, cb = (t >> 6) * 16;
        const float* ip = in + ((size_t)b * C2_ + c0) * M_ + m0;
        for (int i = 0; i < 16; ++i)
            tile[cb + i][ml] = f2b(ip[(size_t)(cb + i) * M_ + ml]);
    }
    __syncthreads();
    {
        int cl = t & 63, mb = (t >> 6) * 16;
        for (int i = 0; i < 16; ++i)
            out[((size_t)b * M_ + m0 + mb + i) * C2_ + c0 + cl] = tile[cl][mb + i];
    }
}

// ---------------------------------------------------------------------------
// 3-NN (fp64 ranking) + weighted interpolation -> interp (P, 512) bf16.
// One wave per unknown point, 64 points per 256-thread block.
// ---------------------------------------------------------------------------
__device__ __forceinline__ void ins3d(double d, int m,
                                      double& d0, int& i0, double& d1, int& i1,
                                      double& d2, int& i2) {
    if (d < d2 || (d == d2 && m < i2)) {
        d2 = d; i2 = m;
        if (d2 < d1 || (d2 == d1 && i2 < i1)) { double td = d1; d1 = d2; d2 = td; int ti = i1; i1 = i2; i2 = ti; }
        if (d1 < d0 || (d1 == d0 && i1 < i0)) { double td = d0; d0 = d1; d1 = td; int ti = i0; i0 = i1; i1 = ti; }
    }
}

__global__ __launch_bounds__(256) void interp_k(
    const float* __restrict__ unknown, const float* __restrict__ known,
    const ushort_t* __restrict__ kfT, ushort_t* __restrict__ interp) {
    __shared__ float kx[M_], ky[M_], kz[M_];
    __shared__ double ksd[M_];
    int blk = blockIdx.x;            // 1024 blocks
    int b = blk >> 6;                // 64 blocks per batch
    int n0 = (blk & 63) * 64;
    int t = threadIdx.x, lane = t & 63, wid = t >> 6;

    for (int m = t; m < M_; m += 256) {
        float x = known[((size_t)b * M_ + m) * 3 + 0];
        float y = known[((size_t)b * M_ + m) * 3 + 1];
        float z = known[((size_t)b * M_ + m) * 3 + 2];
        kx[m] = x; ky[m] = y; kz[m] = z;
        ksd[m] = (double)x * x + (double)y * y + (double)z * z;
    }
    __syncthreads();

    for (int it = 0; it < 16; ++it) {
        int n = n0 + wid * 16 + it;
        double qx = unknown[((size_t)b * N_ + n) * 3 + 0];
        double qy = unknown[((size_t)b * N_ + n) * 3 + 1];
        double qz = unknown[((size_t)b * N_ + n) * 3 + 2];
        double qs = qx * qx + qy * qy + qz * qz;

        double d0 = 1e300, d1 = 1e300, d2 = 1e300;
        int i0 = 0x7fffffff, i1 = 0x7fffffff, i2 = 0x7fffffff;
        for (int j = 0; j < 16; ++j) {
            int m = lane + 64 * j;
            double dot = qx * (double)kx[m] + qy * (double)ky[m] + qz * (double)kz[m];
            double d = qs + ksd[m] - 2.0 * dot;
            ins3d(d, m, d0, i0, d1, i1, d2, i2);
        }
        for (int off = 32; off; off >>= 1) {
            double e0 = __shfl_xor(d0, off), e1 = __shfl_xor(d1, off), e2 = __shfl_xor(d2, off);
            int    j0 = __shfl_xor(i0, off), j1 = __shfl_xor(i1, off), j2 = __shfl_xor(i2, off);
            ins3d(e0, j0, d0, i0, d1, i1, d2, i2);
            ins3d(e1, j1, d0, i0, d1, i1, d2, i2);
            ins3d(e2, j2, d0, i0, d1, i1, d2, i2);
        }
        double w0 = 1.0 / (d0 + 1e-8);
        double w1 = 1.0 / (d1 + 1e-8);
        double w2 = 1.0 / (d2 + 1e-8);
        double inv = 1.0 / (w0 + w1 + w2);
        float f0 = (float)(w0 * inv), f1 = (float)(w1 * inv), f2 = (float)(w2 * inv);

        const uint4* r0 = (const uint4*)(kfT + ((size_t)b * M_ + i0) * C2_);
        const uint4* r1 = (const uint4*)(kfT + ((size_t)b * M_ + i1) * C2_);
        const uint4* r2 = (const uint4*)(kfT + ((size_t)b * M_ + i2) * C2_);
        uint4 v0 = r0[lane], v1 = r1[lane], v2 = r2[lane];
        const ushort_t* p0 = (const ushort_t*)&v0;
        const ushort_t* p1 = (const ushort_t*)&v1;
        const ushort_t* p2 = (const ushort_t*)&v2;
        uint4 o; ushort_t* po = (ushort_t*)&o;
        for (int j = 0; j < 8; ++j) {
            float f = f0 * b2f(p0[j]) + f1 * b2f(p1[j]) + f2 * b2f(p2[j]);
            po[j] = f2b(f);
        }
        ((uint4*)(interp + ((size_t)b * N_ + n) * C2_))[lane] = o;
    }
}

// ---------------------------------------------------------------------------
// GEMM1: x1(P,256) = [ufT | interp] (P,768) * w1b(256,768)^T, bf16 MFMA.
// K<256: A staged straight from uf f32 (fused transpose+cvt via LDS).
// K>=256: A staged from interp bf16 via global_load_lds (16B).
// ---------------------------------------------------------------------------
__global__ __launch_bounds__(256) void gemm1_k(
    const float* __restrict__ uf, const ushort_t* __restrict__ interp,
    const ushort_t* __restrict__ w1b, ushort_t* __restrict__ x1) {
    __shared__ ushort_t As[128 * 32];
    __shared__ ushort_t Bs[128 * 32];
    int t = threadIdx.x, lane = t & 63, wid = t >> 6;
    int wm = wid & 1, wn = wid >> 1;
    int row0 = blockIdx.x * 128, col0 = blockIdx.y * 128;
    int quad = lane >> 4, l15 = lane & 15;
    int srow = lane >> 2, kc = lane & 3;
    int b = row0 >> 12, nb = row0 & 4095;   // 128 points always within one batch
    uint_t* As32 = (uint_t*)As;

    f32x4 acc[4][4] = {};

    for (int k0 = 0; k0 < K1_; k0 += 32) {
        if (k0 < C1_) {
            const float* up = uf + ((size_t)b * C1_ + k0) * N_ + nb;
            for (int i = 0; i < 8; ++i) {
                int id = i * 256 + t;
                int kkp = id >> 7;           // channel pair 0..15
                int r = id & 127;            // point 0..127
                float v0 = up[(size_t)(2 * kkp) * N_ + r];
                float v1 = up[(size_t)(2 * kkp + 1) * N_ + r];
                As32[r * 16 + kkp] = (uint_t)f2b(v0) | ((uint_t)f2b(v1) << 16);
            }
        } else {
            for (int j = 0; j < 2; ++j) {
                int rbase = wid * 32 + j * 16;
                async16(interp + ((size_t)(row0 + rbase + srow)) * C2_ + (k0 - C1_) + kc * 8,
                        &As[rbase * 32]);
            }
        }
        for (int j = 0; j < 2; ++j) {
            int rbase = wid * 32 + j * 16;
            async16(w1b + ((size_t)(col0 + rbase + srow)) * K1_ + k0 + kc * 8,
                    &Bs[rbase * 32]);
        }
        __syncthreads();

        s16x8 af[4], bfr[4];
        for (int i = 0; i < 4; ++i)
            af[i] = *(const s16x8*)&As[(wm * 64 + i * 16 + l15) * 32 + quad * 8];
        for (int j = 0; j < 4; ++j)
            bfr[j] = *(const s16x8*)&Bs[(wn * 64 + j * 16 + l15) * 32 + quad * 8];
        for (int i = 0; i < 4; ++i)
            for (int j = 0; j < 4; ++j)
                acc[i][j] = __builtin_amdgcn_mfma_f32_16x16x32_bf16(
                    af[i], bfr[j], acc[i][j], 0, 0, 0);
        __syncthreads();
    }

    for (int i = 0; i < 4; ++i)
        for (int j = 0; j < 4; ++j)
            for (int r = 0; r < 4; ++r) {
                int m = row0 + wm * 64 + i * 16 + quad * 4 + r;
                int n = col0 + wn * 64 + j * 16 + l15;
                x1[(size_t)m * H_ + n] = f2b(acc[i][j][r]);
            }
}

// ---------------------------------------------------------------------------
// GEMM2 (plain): C(P,256) = A(P,K) * Bw(256,K)^T, bf16, K param (=256).
// ---------------------------------------------------------------------------
__global__ __launch_bounds__(256) void gemm_bt_k(
    const ushort_t* __restrict__ A, const ushort_t* __restrict__ Bw,
    ushort_t* __restrict__ C, int K) {
    __shared__ ushort_t As[128 * 32];
    __shared__ ushort_t Bs[128 * 32];
    int t = threadIdx.x, lane = t & 63, wid = t >> 6;
    int wm = wid & 1, wn = wid >> 1;
    int row0 = blockIdx.x * 128, col0 = blockIdx.y * 128;
    int quad = lane >> 4, l15 = lane & 15;
    int srow = lane >> 2, kc = lane & 3;

    f32x4 acc[4][4] = {};

    for (int k0 = 0; k0 < K; k0 += 32) {
        for (int j = 0; j < 2; ++j) {
            int rbase = wid * 32 + j * 16;
            async16(A + ((size_t)(row0 + rbase + srow)) * K + k0 + kc * 8,
                    &As[rbase * 32]);
            async16(Bw + ((size_t)(col0 + rbase + srow)) * K + k0 + kc * 8,
                    &Bs[rbase * 32]);
        }
        __syncthreads();

        s16x8 af[4], bfr[4];
        for (int i = 0; i < 4; ++i)
            af[i] = *(const s16x8*)&As[(wm * 64 + i * 16 + l15) * 32 + quad * 8];
        for (int j = 0; j < 4; ++j)
            bfr[j] = *(const s16x8*)&Bs[(wn * 64 + j * 16 + l15) * 32 + quad * 8];
        for (int i = 0; i < 4; ++i)
            for (int j = 0; j < 4; ++j)
                acc[i][j] = __builtin_amdgcn_mfma_f32_16x16x32_bf16(
                    af[i], bfr[j], acc[i][j], 0, 0, 0);
        __syncthreads();
    }

    for (int i = 0; i < 4; ++i)
        for (int j = 0; j < 4; ++j)
            for (int r = 0; r < 4; ++r) {
                int m = row0 + wm * 64 + i * 16 + quad * 4 + r;
                int n = col0 + wn * 64 + j * 16 + l15;
                C[(size_t)m * H_ + n] = f2b(acc[i][j][r]);
            }
}

// ---------------------------------------------------------------------------
// Per-channel sum / sumsq over (P, 256) bf16.
// ---------------------------------------------------------------------------
__global__ __launch_bounds__(256) void stats_k(
    const ushort_t* __restrict__ x, float* __restrict__ sum, float* __restrict__ sq) {
    int t = threadIdx.x;
    int r0 = blockIdx.x * 256;
    float s = 0.f, q = 0.f;
    for (int r = 0; r < 256; ++r) {
        float v = b2f(x[(size_t)(r0 + r) * 256 + t]);
        s += v; q += v * v;
    }
    atomicAdd(&sum[t], s);
    atomicAdd(&sq[t], q);
}

__global__ __launch_bounds__(256) void coef_k(
    const float* __restrict__ sum, const float* __restrict__ sq,
    const float* __restrict__ g, const float* __restrict__ bt,
    float* __restrict__ a, float* __restrict__ c) {
    int t = threadIdx.x;
    float mean = sum[t] * (1.0f / P_);
    float var  = sq[t] * (1.0f / P_) - mean * mean;
    float ai = g[t] * rsqrtf(var + 1e-5f);
    a[t] = ai;
    c[t] = bt[t] - mean * ai;
}

// BN + ReLU elementwise: x1 (P,256) bf16 -> h1 bf16, one uint4 (8 elems)/thread
__global__ __launch_bounds__(256) void bnrelu_k(
    const uint4* __restrict__ x, const float* __restrict__ a,
    const float* __restrict__ c, uint4* __restrict__ h) {
    size_t i = (size_t)blockIdx.x * 256 + threadIdx.x;   // 2,097,152 uint4s
    uint4 v = x[i];
    int chb = (int)((i * 8) & 255);
    const ushort_t* pv = (const ushort_t*)&v;
    uint4 o; ushort_t* po = (ushort_t*)&o;
    for (int j = 0; j < 8; ++j) {
        float f = b2f(pv[j]);
        f = a[chb + j] * f + c[chb + j];
        po[j] = f2b(fmaxf(f, 0.0f));
    }
    h[i] = o;
}

// BN + ReLU + transpose: x2 (P,256) bf16 -> out (B,256,N) f32, 64x64 tiles
__global__ __launch_bounds__(256) void final_k(
    const ushort_t* __restrict__ x2, const float* __restrict__ a,
    const float* __restrict__ c, float* __restrict__ out) {
    __shared__ float tile[64][65];
    int n0 = blockIdx.x * 64, c0 = blockIdx.y * 64, b = blockIdx.z;
    int t = threadIdx.x;
    {
        int cl = t & 63, pb = (t >> 6) * 16;
        float av = a[c0 + cl], cv = c[c0 + cl];
        for (int i = 0; i < 16; ++i) {
            float v = b2f(x2[((size_t)b * N_ + n0 + pb + i) * H_ + c0 + cl]);
            tile[cl][pb + i] = fmaxf(av * v + cv, 0.0f);
        }
    }
    __syncthreads();
    {
        int nl = t & 63, cb = (t >> 6) * 16;
        for (int i = 0; i < 16; ++i)
            out[((size_t)b * H_ + c0 + cb + i) * N_ + n0 + nl] = tile[cb + i][nl];
    }
}

// ---------------------------------------------------------------------------
extern "C" void kernel_launch(void* const* d_in, const int* in_sizes, int n_in,
                              void* d_out, int out_size, void* d_ws, size_t ws_size,
                              hipStream_t stream) {
    const float* unknown = (const float*)d_in[0];
    const float* known   = (const float*)d_in[1];
    const float* uf      = (const float*)d_in[2];
    const float* kf      = (const float*)d_in[3];
    const float* w1      = (const float*)d_in[4];
    const float* g1      = (const float*)d_in[5];
    const float* b1      = (const float*)d_in[6];
    const float* w2      = (const float*)d_in[7];
    const float* g2      = (const float*)d_in[8];
    const float* b2      = (const float*)d_in[9];
    float* out = (float*)d_out;

    char* ws = (char*)d_ws;
    // [0, 8K): stats — sum1,sq1,sum2,sq2,a1,c1,a2,c2 (8 x 256 f32)
    float* sum1 = (float*)ws;
    float* sq1  = sum1 + 256;
    float* sum2 = sum1 + 512;
    float* sq2  = sum1 + 768;
    float* a1   = sum1 + 1024;
    float* c1   = sum1 + 1280;
    float* a2   = sum1 + 1536;
    float* c2   = sum1 + 1792;
    // [8K, ~520K): converted weights
    ushort_t* w1b = (ushort_t*)(ws + 8192);                       // 384 KB
    ushort_t* w2b = (ushort_t*)(ws + 8192 + (size_t)H_ * K1_ * 2); // 128 KB
    const size_t MB = 1024 * 1024;
    ushort_t* kfT    = (ushort_t*)(ws + 1 * MB);    // 16 MB  [dead after interp_k]
    ushort_t* interp = (ushort_t*)(ws + 17 * MB);   // 64 MB  [dead after gemm1]
    ushort_t* h1     = (ushort_t*)(ws + 17 * MB);   // 32 MB  (over interp lo half)
    ushort_t* x2     = (ushort_t*)(ws + 49 * MB);   // 32 MB  (over interp hi half)
    ushort_t* x1     = (ushort_t*)(ws + 81 * MB);   // 32 MB  -> total 113 MB

    zero_k<<<8, 256, 0, stream>>>(sum1);
    cvtw_k<<<1024, 256, 0, stream>>>(w1, w2, w1b, w2b);
    tkf_k<<<dim3(16, 8, 16), 256, 0, stream>>>(kf, kfT);
    interp_k<<<1024, 256, 0, stream>>>(unknown, known, kfT, interp);
    gemm1_k<<<dim3(512, 2), 256, 0, stream>>>(uf, interp, w1b, x1);
    stats_k<<<256, 256, 0, stream>>>(x1, sum1, sq1);
    coef_k<<<1, 256, 0, stream>>>(sum1, sq1, g1, b1, a1, c1);
    bnrelu_k<<<8192, 256, 0, stream>>>((const uint4*)x1, a1, c1, (uint4*)h1);
    gemm_bt_k<<<dim3(512, 2), 256, 0, stream>>>(h1, w2b, x2, H_);
    stats_k<<<256, 256, 0, stream>>>(x2, sum2, sq2);
    coef_k<<<1, 256, 0, stream>>>(sum2, sq2, g2, b2, a2, c2);
    final_k<<<dim3(64, 4, 16), 256, 0, stream>>>(x2, a2, c2, out);
}

// Round 3
// 510.618 us; speedup vs baseline: 1.0006x; 1.0006x over previous
//
#include <hip/hip_runtime.h>
#include <stdint.h>

#define B_   16
#define N_   4096
#define M_   1024
#define C1_  256
#define C2_  512
#define H_   256
#define K1_  768      // C1+C2
#define P_   65536    // B*N

typedef unsigned int  uint_t;
typedef unsigned short ushort_t;
typedef __attribute__((ext_vector_type(4))) float f32x4;
typedef __attribute__((ext_vector_type(8))) short s16x8;

__device__ __forceinline__ float b2f(ushort_t u) {
    union { uint_t i; float f; } v; v.i = ((uint_t)u) << 16; return v.f;
}
__device__ __forceinline__ ushort_t f2b(float f) {
    union { float f; uint_t i; } v; v.f = f;
    uint_t x = v.i;
    return (ushort_t)((x + 0x7fffu + ((x >> 16) & 1u)) >> 16);  // RNE
}

__device__ __forceinline__ void async16(const void* g, void* l) {
    __builtin_amdgcn_global_load_lds(
        (const __attribute__((address_space(1))) uint_t*)g,
        (__attribute__((address_space(3))) uint_t*)l, 16, 0, 0);
}

// ---------------------------------------------------------------------------
__global__ __launch_bounds__(256) void zero_k(float* __restrict__ p) {
    p[blockIdx.x * 256 + threadIdx.x] = 0.0f;
}

// ---------------------------------------------------------------------------
// Convert w1 (256x768 f32) and w2 (256x256 f32) to bf16.
// ---------------------------------------------------------------------------
__global__ __launch_bounds__(256) void cvtw_k(
    const float* __restrict__ w1, const float* __restrict__ w2,
    ushort_t* __restrict__ w1b, ushort_t* __restrict__ w2b) {
    int t = blockIdx.x * 256 + threadIdx.x;   // 262144 total
    if (t < H_ * K1_) w1b[t] = f2b(w1[t]);
    else { int u = t - H_ * K1_; w2b[u] = f2b(w2[u]); }
}

// ---------------------------------------------------------------------------
// known_feats (B, 512, 1024) f32 -> kfT (B, 1024, 512) bf16, 64x64 LDS tiles
// ---------------------------------------------------------------------------
__global__ __launch_bounds__(256) void tkf_k(
    const float* __restrict__ in, ushort_t* __restrict__ out) {
    __shared__ ushort_t tile[64][65];
    int m0 = blockIdx.x * 64, c0 = blockIdx.y * 64, b = blockIdx.z;
    int t = threadIdx.x;
    {
        int ml = t & 63, cb = (t >> 6) * 16;
        const float* ip = in + ((size_t)b * C2_ + c0) * M_ + m0;
        for (int i = 0; i < 16; ++i)
            tile[cb + i][ml] = f2b(ip[(size_t)(cb + i) * M_ + ml]);
    }
    __syncthreads();
    {
        int cl = t & 63, mb = (t >> 6) * 16;
        for (int i = 0; i < 16; ++i)
            out[((size_t)b * M_ + m0 + mb + i) * C2_ + c0 + cl] = tile[cl][mb + i];
    }
}

// ---------------------------------------------------------------------------
// 3-NN, one THREAD per point. All lanes scan the same candidate (LDS
// broadcast); fp64 ranking identical to previous passing round; 4 interleaved
// streams for ILP; min-index tie-break preserved through the stream merge.
// ---------------------------------------------------------------------------
__device__ __forceinline__ void ins3d(double d, int m,
                                      double& d0, int& i0, double& d1, int& i1,
                                      double& d2, int& i2) {
    if (d < d2 || (d == d2 && m < i2)) {
        d2 = d; i2 = m;
        if (d2 < d1 || (d2 == d1 && i2 < i1)) { double td = d1; d1 = d2; d2 = td; int ti = i1; i1 = i2; i2 = ti; }
        if (d1 < d0 || (d1 == d0 && i1 < i0)) { double td = d0; d0 = d1; d1 = td; int ti = i0; i0 = i1; i1 = ti; }
    }
}

__global__ __launch_bounds__(256) void knn_k(
    const float* __restrict__ unknown, const float* __restrict__ known,
    int4* __restrict__ idx3, float4* __restrict__ wgt3) {
    __shared__ float kx[M_], ky[M_], kz[M_];
    __shared__ double ksd[M_];
    int b = blockIdx.x >> 4;          // 256 blocks, 16 per batch
    int n0 = (blockIdx.x & 15) * 256;
    int t = threadIdx.x;

    for (int m = t; m < M_; m += 256) {
        float x = known[((size_t)b * M_ + m) * 3 + 0];
        float y = known[((size_t)b * M_ + m) * 3 + 1];
        float z = known[((size_t)b * M_ + m) * 3 + 2];
        kx[m] = x; ky[m] = y; kz[m] = z;
        ksd[m] = (double)x * x + (double)y * y + (double)z * z;
    }
    __syncthreads();

    int n = n0 + t;
    double qx = (double)unknown[((size_t)b * N_ + n) * 3 + 0];
    double qy = (double)unknown[((size_t)b * N_ + n) * 3 + 1];
    double qz = (double)unknown[((size_t)b * N_ + n) * 3 + 2];
    double qs = qx * qx + qy * qy + qz * qz;

    double D0[4], D1[4], D2[4];
    int    I0[4], I1[4], I2[4];
#pragma unroll
    for (int s = 0; s < 4; ++s) {
        D0[s] = 1e300; D1[s] = 1e300; D2[s] = 1e300;
        I0[s] = 0x7fffffff; I1[s] = 0x7fffffff; I2[s] = 0x7fffffff;
    }

    for (int j = 0; j < 256; ++j) {
#pragma unroll
        for (int s = 0; s < 4; ++s) {
            int m = 4 * j + s;
            double dot = qx * (double)kx[m] + qy * (double)ky[m] + qz * (double)kz[m];
            double d = qs + ksd[m] - 2.0 * dot;
            ins3d(d, m, D0[s], I0[s], D1[s], I1[s], D2[s], I2[s]);
        }
    }
    // merge streams 1..3 into stream 0 (index tie-break handled by ins3d)
#pragma unroll
    for (int s = 1; s < 4; ++s) {
        ins3d(D0[s], I0[s], D0[0], I0[0], D1[0], I1[0], D2[0], I2[0]);
        ins3d(D1[s], I1[s], D0[0], I0[0], D1[0], I1[0], D2[0], I2[0]);
        ins3d(D2[s], I2[s], D0[0], I0[0], D1[0], I1[0], D2[0], I2[0]);
    }

    double w0 = 1.0 / (D0[0] + 1e-8);
    double w1 = 1.0 / (D1[0] + 1e-8);
    double w2 = 1.0 / (D2[0] + 1e-8);
    double inv = 1.0 / (w0 + w1 + w2);

    size_t p = (size_t)b * N_ + n;
    idx3[p] = make_int4(I0[0], I1[0], I2[0], 0);
    wgt3[p] = make_float4((float)(w0 * inv), (float)(w1 * inv), (float)(w2 * inv), 0.f);
}

// ---------------------------------------------------------------------------
// Weighted gather: wave per point, 8 points/wave, idx/wgt prefetch depth 1.
// interp (P, 512) bf16.
// ---------------------------------------------------------------------------
__global__ __launch_bounds__(256) void gather_k(
    const int4* __restrict__ idx3, const float4* __restrict__ wgt3,
    const ushort_t* __restrict__ kfT, ushort_t* __restrict__ interp) {
    int blk = blockIdx.x;             // 2048 blocks
    int b = blk >> 7;                 // 128 blocks per batch
    int n0 = (blk & 127) * 32;
    int lane = threadIdx.x & 63, wid = threadIdx.x >> 6;

    size_t pbase = (size_t)b * N_ + n0 + wid * 8;
    int4 id = idx3[pbase];
    float4 w = wgt3[pbase];
    for (int it = 0; it < 8; ++it) {
        int4 idn; float4 wn;
        if (it < 7) { idn = idx3[pbase + it + 1]; wn = wgt3[pbase + it + 1]; }
        const uint4* r0 = (const uint4*)(kfT + ((size_t)b * M_ + id.x) * C2_);
        const uint4* r1 = (const uint4*)(kfT + ((size_t)b * M_ + id.y) * C2_);
        const uint4* r2 = (const uint4*)(kfT + ((size_t)b * M_ + id.z) * C2_);
        uint4 v0 = r0[lane], v1 = r1[lane], v2 = r2[lane];
        const ushort_t* p0 = (const ushort_t*)&v0;
        const ushort_t* p1 = (const ushort_t*)&v1;
        const ushort_t* p2 = (const ushort_t*)&v2;
        uint4 o; ushort_t* po = (ushort_t*)&o;
        for (int j = 0; j < 8; ++j) {
            float f = w.x * b2f(p0[j]) + w.y * b2f(p1[j]) + w.z * b2f(p2[j]);
            po[j] = f2b(f);
        }
        ((uint4*)(interp + (pbase + it) * C2_))[lane] = o;
        id = idn; w = wn;
    }
}

// ---------------------------------------------------------------------------
// GEMM1: x1(P,256) = [ufT | interp] (P,768) * w1b(256,768)^T, bf16 MFMA.
// K<256: A staged straight from uf f32 (fused transpose+cvt via LDS).
// K>=256: A staged from interp bf16 via global_load_lds (16B).
// ---------------------------------------------------------------------------
__global__ __launch_bounds__(256) void gemm1_k(
    const float* __restrict__ uf, const ushort_t* __restrict__ interp,
    const ushort_t* __restrict__ w1b, ushort_t* __restrict__ x1) {
    __shared__ ushort_t As[128 * 32];
    __shared__ ushort_t Bs[128 * 32];
    int t = threadIdx.x, lane = t & 63, wid = t >> 6;
    int wm = wid & 1, wn = wid >> 1;
    int row0 = blockIdx.x * 128, col0 = blockIdx.y * 128;
    int quad = lane >> 4, l15 = lane & 15;
    int srow = lane >> 2, kc = lane & 3;
    int b = row0 >> 12, nb = row0 & 4095;   // 128 points always within one batch
    uint_t* As32 = (uint_t*)As;

    f32x4 acc[4][4] = {};

    for (int k0 = 0; k0 < K1_; k0 += 32) {
        if (k0 < C1_) {
            const float* up = uf + ((size_t)b * C1_ + k0) * N_ + nb;
            for (int i = 0; i < 8; ++i) {
                int id = i * 256 + t;
                int kkp = id >> 7;           // channel pair 0..15
                int r = id & 127;            // point 0..127
                float v0 = up[(size_t)(2 * kkp) * N_ + r];
                float v1 = up[(size_t)(2 * kkp + 1) * N_ + r];
                As32[r * 16 + kkp] = (uint_t)f2b(v0) | ((uint_t)f2b(v1) << 16);
            }
        } else {
            for (int j = 0; j < 2; ++j) {
                int rbase = wid * 32 + j * 16;
                async16(interp + ((size_t)(row0 + rbase + srow)) * C2_ + (k0 - C1_) + kc * 8,
                        &As[rbase * 32]);
            }
        }
        for (int j = 0; j < 2; ++j) {
            int rbase = wid * 32 + j * 16;
            async16(w1b + ((size_t)(col0 + rbase + srow)) * K1_ + k0 + kc * 8,
                    &Bs[rbase * 32]);
        }
        __syncthreads();

        s16x8 af[4], bfr[4];
        for (int i = 0; i < 4; ++i)
            af[i] = *(const s16x8*)&As[(wm * 64 + i * 16 + l15) * 32 + quad * 8];
        for (int j = 0; j < 4; ++j)
            bfr[j] = *(const s16x8*)&Bs[(wn * 64 + j * 16 + l15) * 32 + quad * 8];
        for (int i = 0; i < 4; ++i)
            for (int j = 0; j < 4; ++j)
                acc[i][j] = __builtin_amdgcn_mfma_f32_16x16x32_bf16(
                    af[i], bfr[j], acc[i][j], 0, 0, 0);
        __syncthreads();
    }

    for (int i = 0; i < 4; ++i)
        for (int j = 0; j < 4; ++j)
            for (int r = 0; r < 4; ++r) {
                int m = row0 + wm * 64 + i * 16 + quad * 4 + r;
                int n = col0 + wn * 64 + j * 16 + l15;
                x1[(size_t)m * H_ + n] = f2b(acc[i][j][r]);
            }
}

// ---------------------------------------------------------------------------
// GEMM2 (plain): C(P,256) = A(P,K) * Bw(256,K)^T, bf16, K param (=256).
// ---------------------------------------------------------------------------
__global__ __launch_bounds__(256) void gemm_bt_k(
    const ushort_t* __restrict__ A, const ushort_t* __restrict__ Bw,
    ushort_t* __restrict__ C, int K) {
    __shared__ ushort_t As[128 * 32];
    __shared__ ushort_t Bs[128 * 32];
    int t = threadIdx.x, lane = t & 63, wid = t >> 6;
    int wm = wid & 1, wn = wid >> 1;
    int row0 = blockIdx.x * 128, col0 = blockIdx.y * 128;
    int quad = lane >> 4, l15 = lane & 15;
    int srow = lane >> 2, kc = lane & 3;

    f32x4 acc[4][4] = {};

    for (int k0 = 0; k0 < K; k0 += 32) {
        for (int j = 0; j < 2; ++j) {
            int rbase = wid * 32 + j * 16;
            async16(A + ((size_t)(row0 + rbase + srow)) * K + k0 + kc * 8,
                    &As[rbase * 32]);
            async16(Bw + ((size_t)(col0 + rbase + srow)) * K + k0 + kc * 8,
                    &Bs[rbase * 32]);
        }
        __syncthreads();

        s16x8 af[4], bfr[4];
        for (int i = 0; i < 4; ++i)
            af[i] = *(const s16x8*)&As[(wm * 64 + i * 16 + l15) * 32 + quad * 8];
        for (int j = 0; j < 4; ++j)
            bfr[j] = *(const s16x8*)&Bs[(wn * 64 + j * 16 + l15) * 32 + quad * 8];
        for (int i = 0; i < 4; ++i)
            for (int j = 0; j < 4; ++j)
                acc[i][j] = __builtin_amdgcn_mfma_f32_16x16x32_bf16(
                    af[i], bfr[j], acc[i][j], 0, 0, 0);
        __syncthreads();
    }

    for (int i = 0; i < 4; ++i)
        for (int j = 0; j < 4; ++j)
            for (int r = 0; r < 4; ++r) {
                int m = row0 + wm * 64 + i * 16 + quad * 4 + r;
                int n = col0 + wn * 64 + j * 16 + l15;
                C[(size_t)m * H_ + n] = f2b(acc[i][j][r]);
            }
}

// ---------------------------------------------------------------------------
__global__ __launch_bounds__(256) void stats_k(
    const ushort_t* __restrict__ x, float* __restrict__ sum, float* __restrict__ sq) {
    int t = threadIdx.x;
    int r0 = blockIdx.x * 256;
    float s = 0.f, q = 0.f;
    for (int r = 0; r < 256; ++r) {
        float v = b2f(x[(size_t)(r0 + r) * 256 + t]);
        s += v; q += v * v;
    }
    atomicAdd(&sum[t], s);
    atomicAdd(&sq[t], q);
}

__global__ __launch_bounds__(256) void coef_k(
    const float* __restrict__ sum, const float* __restrict__ sq,
    const float* __restrict__ g, const float* __restrict__ bt,
    float* __restrict__ a, float* __restrict__ c) {
    int t = threadIdx.x;
    float mean = sum[t] * (1.0f / P_);
    float var  = sq[t] * (1.0f / P_) - mean * mean;
    float ai = g[t] * rsqrtf(var + 1e-5f);
    a[t] = ai;
    c[t] = bt[t] - mean * ai;
}

// BN + ReLU elementwise: x1 (P,256) bf16 -> h1 bf16, one uint4 (8 elems)/thread
__global__ __launch_bounds__(256) void bnrelu_k(
    const uint4* __restrict__ x, const float* __restrict__ a,
    const float* __restrict__ c, uint4* __restrict__ h) {
    size_t i = (size_t)blockIdx.x * 256 + threadIdx.x;   // 2,097,152 uint4s
    uint4 v = x[i];
    int chb = (int)((i * 8) & 255);
    const ushort_t* pv = (const ushort_t*)&v;
    uint4 o; ushort_t* po = (ushort_t*)&o;
    for (int j = 0; j < 8; ++j) {
        float f = b2f(pv[j]);
        f = a[chb + j] * f + c[chb + j];
        po[j] = f2b(fmaxf(f, 0.0f));
    }
    h[i] = o;
}

// BN + ReLU + transpose: x2 (P,256) bf16 -> out (B,256,N) f32, 64x64 tiles
__global__ __launch_bounds__(256) void final_k(
    const ushort_t* __restrict__ x2, const float* __restrict__ a,
    const float* __restrict__ c, float* __restrict__ out) {
    __shared__ float tile[64][65];
    int n0 = blockIdx.x * 64, c0 = blockIdx.y * 64, b = blockIdx.z;
    int t = threadIdx.x;
    {
        int cl = t & 63, pb = (t >> 6) * 16;
        float av = a[c0 + cl], cv = c[c0 + cl];
        for (int i = 0; i < 16; ++i) {
            float v = b2f(x2[((size_t)b * N_ + n0 + pb + i) * H_ + c0 + cl]);
            tile[cl][pb + i] = fmaxf(av * v + cv, 0.0f);
        }
    }
    __syncthreads();
    {
        int nl = t & 63, cb = (t >> 6) * 16;
        for (int i = 0; i < 16; ++i)
            out[((size_t)b * H_ + c0 + cb + i) * N_ + n0 + nl] = tile[cb + i][nl];
    }
}

// ---------------------------------------------------------------------------
extern "C" void kernel_launch(void* const* d_in, const int* in_sizes, int n_in,
                              void* d_out, int out_size, void* d_ws, size_t ws_size,
                              hipStream_t stream) {
    const float* unknown = (const float*)d_in[0];
    const float* known   = (const float*)d_in[1];
    const float* uf      = (const float*)d_in[2];
    const float* kf      = (const float*)d_in[3];
    const float* w1      = (const float*)d_in[4];
    const float* g1      = (const float*)d_in[5];
    const float* b1      = (const float*)d_in[6];
    const float* w2      = (const float*)d_in[7];
    const float* g2      = (const float*)d_in[8];
    const float* b2      = (const float*)d_in[9];
    float* out = (float*)d_out;

    char* ws = (char*)d_ws;
    // [0, 8K): stats — sum1,sq1,sum2,sq2,a1,c1,a2,c2 (8 x 256 f32)
    float* sum1 = (float*)ws;
    float* sq1  = sum1 + 256;
    float* sum2 = sum1 + 512;
    float* sq2  = sum1 + 768;
    float* a1   = sum1 + 1024;
    float* c1   = sum1 + 1280;
    float* a2   = sum1 + 1536;
    float* c2   = sum1 + 1792;
    // [8K, ~520K): converted weights
    ushort_t* w1b = (ushort_t*)(ws + 8192);                        // 384 KB
    ushort_t* w2b = (ushort_t*)(ws + 8192 + (size_t)H_ * K1_ * 2); // 128 KB
    const size_t MB = 1024 * 1024;
    ushort_t* kfT    = (ushort_t*)(ws + 1 * MB);    // 16 MB  [dead after gather_k]
    ushort_t* interp = (ushort_t*)(ws + 17 * MB);   // 64 MB  [dead after gemm1]
    ushort_t* h1     = (ushort_t*)(ws + 17 * MB);   // 32 MB  (over interp lo half)
    ushort_t* x2     = (ushort_t*)(ws + 49 * MB);   // 32 MB  (over interp hi half)
    ushort_t* x1     = (ushort_t*)(ws + 81 * MB);   // 32 MB
    // knn outputs live in the (not-yet-written) x1 region; consumed by gather_k
    // strictly before gemm1 writes x1 (same stream, serialized).
    int4*   idx3 = (int4*)(ws + 81 * MB);           // 1 MB
    float4* wgt3 = (float4*)(ws + 82 * MB);         // 1 MB  -> peak 113 MB

    zero_k<<<8, 256, 0, stream>>>(sum1);
    cvtw_k<<<1024, 256, 0, stream>>>(w1, w2, w1b, w2b);
    tkf_k<<<dim3(16, 8, 16), 256, 0, stream>>>(kf, kfT);
    knn_k<<<256, 256, 0, stream>>>(unknown, known, idx3, wgt3);
    gather_k<<<2048, 256, 0, stream>>>(idx3, wgt3, kfT, interp);
    gemm1_k<<<dim3(512, 2), 256, 0, stream>>>(uf, interp, w1b, x1);
    stats_k<<<256, 256, 0, stream>>>(x1, sum1, sq1);
    coef_k<<<1, 256, 0, stream>>>(sum1, sq1, g1, b1, a1, c1);
    bnrelu_k<<<8192, 256, 0, stream>>>((const uint4*)x1, a1, c1, (uint4*)h1);
    gemm_bt_k<<<dim3(512, 2), 256, 0, stream>>>(h1, w2b, x2, H_);
    stats_k<<<256, 256, 0, stream>>>(x2, sum2, sq2);
    coef_k<<<1, 256, 0, stream>>>(sum2, sq2, g2, b2, a2, c2);
    final_k<<<dim3(64, 4, 16), 256, 0, stream>>>(x2, a2, c2, out);
}

// Round 4
// 448.610 us; speedup vs baseline: 1.1389x; 1.1382x over previous
//
#include <hip/hip_runtime.h>
#include <stdint.h>

#define B_   16
#define N_   4096
#define M_   1024
#define C1_  256
#define C2_  512
#define H_   256
#define K1_  768      // C1+C2
#define P_   65536    // B*N

typedef unsigned int  uint_t;
typedef unsigned short ushort_t;
typedef __attribute__((ext_vector_type(4))) float f32x4;
typedef __attribute__((ext_vector_type(8))) short s16x8;

__device__ __forceinline__ float b2f(ushort_t u) {
    union { uint_t i; float f; } v; v.i = ((uint_t)u) << 16; return v.f;
}
__device__ __forceinline__ ushort_t f2b(float f) {
    union { float f; uint_t i; } v; v.f = f;
    uint_t x = v.i;
    return (ushort_t)((x + 0x7fffu + ((x >> 16) & 1u)) >> 16);  // RNE
}

__device__ __forceinline__ void async16(const void* g, void* l) {
    __builtin_amdgcn_global_load_lds(
        (const __attribute__((address_space(1))) uint_t*)g,
        (__attribute__((address_space(3))) uint_t*)l, 16, 0, 0);
}

// ---------------------------------------------------------------------------
__global__ __launch_bounds__(256) void zero_k(float* __restrict__ p) {
    p[blockIdx.x * 256 + threadIdx.x] = 0.0f;
}

// ---------------------------------------------------------------------------
// Convert w1 (256x768 f32) and w2 (256x256 f32) to bf16.
// ---------------------------------------------------------------------------
__global__ __launch_bounds__(256) void cvtw_k(
    const float* __restrict__ w1, const float* __restrict__ w2,
    ushort_t* __restrict__ w1b, ushort_t* __restrict__ w2b) {
    int t = blockIdx.x * 256 + threadIdx.x;   // 262144 total
    if (t < H_ * K1_) w1b[t] = f2b(w1[t]);
    else { int u = t - H_ * K1_; w2b[u] = f2b(w2[u]); }
}

// ---------------------------------------------------------------------------
// known_feats (B, 512, 1024) f32 -> kfT (B, 1024, 512) bf16, 64x64 LDS tiles
// ---------------------------------------------------------------------------
__global__ __launch_bounds__(256) void tkf_k(
    const float* __restrict__ in, ushort_t* __restrict__ out) {
    __shared__ ushort_t tile[64][65];
    int m0 = blockIdx.x * 64, c0 = blockIdx.y * 64, b = blockIdx.z;
    int t = threadIdx.x;
    {
        int ml = t & 63, cb = (t >> 6) * 16;
        const float* ip = in + ((size_t)b * C2_ + c0) * M_ + m0;
        for (int i = 0; i < 16; ++i)
            tile[cb + i][ml] = f2b(ip[(size_t)(cb + i) * M_ + ml]);
    }
    __syncthreads();
    {
        int cl = t & 63, mb = (t >> 6) * 16;
        for (int i = 0; i < 16; ++i)
            out[((size_t)b * M_ + m0 + mb + i) * C2_ + c0 + cl] = tile[cl][mb + i];
    }
}

// ---------------------------------------------------------------------------
// 3-NN, 8 threads per point (candidate dim split 8-way), fp64 ranking,
// min-index tie-break — output identical to the 1-thread/point version.
// 2048 blocks x 256 threads = 32 waves/CU.
// ---------------------------------------------------------------------------
__device__ __forceinline__ void ins3d(double d, int m,
                                      double& d0, int& i0, double& d1, int& i1,
                                      double& d2, int& i2) {
    if (d < d2 || (d == d2 && m < i2)) {
        d2 = d; i2 = m;
        if (d2 < d1 || (d2 == d1 && i2 < i1)) { double td = d1; d1 = d2; d2 = td; int ti = i1; i1 = i2; i2 = ti; }
        if (d1 < d0 || (d1 == d0 && i1 < i0)) { double td = d0; d0 = d1; d1 = td; int ti = i0; i0 = i1; i1 = ti; }
    }
}

__global__ __launch_bounds__(256) void knn_k(
    const float* __restrict__ unknown, const float* __restrict__ known,
    int4* __restrict__ idx3, float4* __restrict__ wgt3) {
    __shared__ float kx[M_], ky[M_], kz[M_];
    __shared__ double ksd[M_];
    int b = blockIdx.x >> 7;               // 2048 blocks, 128 per batch
    int n0 = (blockIdx.x & 127) * 32;      // 32 points per block
    int t = threadIdx.x;
    int pl = t >> 3;                       // point-local 0..31
    int sub = t & 7;                       // candidate slice 0..7

    for (int m = t; m < M_; m += 256) {
        float x = known[((size_t)b * M_ + m) * 3 + 0];
        float y = known[((size_t)b * M_ + m) * 3 + 1];
        float z = known[((size_t)b * M_ + m) * 3 + 2];
        kx[m] = x; ky[m] = y; kz[m] = z;
        ksd[m] = (double)x * x + (double)y * y + (double)z * z;
    }
    __syncthreads();

    int n = n0 + pl;
    double qx = (double)unknown[((size_t)b * N_ + n) * 3 + 0];
    double qy = (double)unknown[((size_t)b * N_ + n) * 3 + 1];
    double qz = (double)unknown[((size_t)b * N_ + n) * 3 + 2];
    double qs = qx * qx + qy * qy + qz * qz;

    double D0[2], D1[2], D2[2];
    int    I0[2], I1[2], I2[2];
#pragma unroll
    for (int s = 0; s < 2; ++s) {
        D0[s] = 1e300; D1[s] = 1e300; D2[s] = 1e300;
        I0[s] = 0x7fffffff; I1[s] = 0x7fffffff; I2[s] = 0x7fffffff;
    }

    int mbase = sub * 128;
    for (int j = 0; j < 64; ++j) {
#pragma unroll
        for (int s = 0; s < 2; ++s) {
            int m = mbase + 2 * j + s;
            double dot = qx * (double)kx[m] + qy * (double)ky[m] + qz * (double)kz[m];
            double d = qs + ksd[m] - 2.0 * dot;
            ins3d(d, m, D0[s], I0[s], D1[s], I1[s], D2[s], I2[s]);
        }
    }
    // merge stream 1 into 0
    ins3d(D0[1], I0[1], D0[0], I0[0], D1[0], I1[0], D2[0], I2[0]);
    ins3d(D1[1], I1[1], D0[0], I0[0], D1[0], I1[0], D2[0], I2[0]);
    ins3d(D2[1], I2[1], D0[0], I0[0], D1[0], I1[0], D2[0], I2[0]);

    // merge across the 8 subs (lane bits 0..2) — sorted-triple butterfly
#pragma unroll
    for (int off = 1; off < 8; off <<= 1) {
        double e0 = __shfl_xor(D0[0], off), e1 = __shfl_xor(D1[0], off), e2 = __shfl_xor(D2[0], off);
        int    j0 = __shfl_xor(I0[0], off), j1 = __shfl_xor(I1[0], off), j2 = __shfl_xor(I2[0], off);
        ins3d(e0, j0, D0[0], I0[0], D1[0], I1[0], D2[0], I2[0]);
        ins3d(e1, j1, D0[0], I0[0], D1[0], I1[0], D2[0], I2[0]);
        ins3d(e2, j2, D0[0], I0[0], D1[0], I1[0], D2[0], I2[0]);
    }

    if (sub == 0) {
        double w0 = 1.0 / (D0[0] + 1e-8);
        double w1 = 1.0 / (D1[0] + 1e-8);
        double w2 = 1.0 / (D2[0] + 1e-8);
        double inv = 1.0 / (w0 + w1 + w2);
        size_t p = (size_t)b * N_ + n;
        idx3[p] = make_int4(I0[0], I1[0], I2[0], 0);
        wgt3[p] = make_float4((float)(w0 * inv), (float)(w1 * inv), (float)(w2 * inv), 0.f);
    }
}

// ---------------------------------------------------------------------------
// Weighted gather: wave per point, 8 points/wave, idx/wgt prefetch depth 1.
// interp (P, 512) bf16.
// ---------------------------------------------------------------------------
__global__ __launch_bounds__(256) void gather_k(
    const int4* __restrict__ idx3, const float4* __restrict__ wgt3,
    const ushort_t* __restrict__ kfT, ushort_t* __restrict__ interp) {
    int blk = blockIdx.x;             // 2048 blocks
    int b = blk >> 7;                 // 128 blocks per batch
    int n0 = (blk & 127) * 32;
    int lane = threadIdx.x & 63, wid = threadIdx.x >> 6;

    size_t pbase = (size_t)b * N_ + n0 + wid * 8;
    int4 id = idx3[pbase];
    float4 w = wgt3[pbase];
    for (int it = 0; it < 8; ++it) {
        int4 idn; float4 wn;
        if (it < 7) { idn = idx3[pbase + it + 1]; wn = wgt3[pbase + it + 1]; }
        const uint4* r0 = (const uint4*)(kfT + ((size_t)b * M_ + id.x) * C2_);
        const uint4* r1 = (const uint4*)(kfT + ((size_t)b * M_ + id.y) * C2_);
        const uint4* r2 = (const uint4*)(kfT + ((size_t)b * M_ + id.z) * C2_);
        uint4 v0 = r0[lane], v1 = r1[lane], v2 = r2[lane];
        const ushort_t* p0 = (const ushort_t*)&v0;
        const ushort_t* p1 = (const ushort_t*)&v1;
        const ushort_t* p2 = (const ushort_t*)&v2;
        uint4 o; ushort_t* po = (ushort_t*)&o;
        for (int j = 0; j < 8; ++j) {
            float f = w.x * b2f(p0[j]) + w.y * b2f(p1[j]) + w.z * b2f(p2[j]);
            po[j] = f2b(f);
        }
        ((uint4*)(interp + (pbase + it) * C2_))[lane] = o;
        id = idn; w = wn;
    }
}

// ---------------------------------------------------------------------------
// GEMM1: x1(P,256) = [ufT | interp] (P,768) * w1b(256,768)^T, bf16 MFMA.
// K<256: A staged straight from uf f32 (fused transpose+cvt via LDS).
// K>=256: A staged from interp bf16 via global_load_lds (16B).
// ---------------------------------------------------------------------------
__global__ __launch_bounds__(256) void gemm1_k(
    const float* __restrict__ uf, const ushort_t* __restrict__ interp,
    const ushort_t* __restrict__ w1b, ushort_t* __restrict__ x1) {
    __shared__ ushort_t As[128 * 32];
    __shared__ ushort_t Bs[128 * 32];
    int t = threadIdx.x, lane = t & 63, wid = t >> 6;
    int wm = wid & 1, wn = wid >> 1;
    int row0 = blockIdx.x * 128, col0 = blockIdx.y * 128;
    int quad = lane >> 4, l15 = lane & 15;
    int srow = lane >> 2, kc = lane & 3;
    int b = row0 >> 12, nb = row0 & 4095;   // 128 points always within one batch
    uint_t* As32 = (uint_t*)As;

    f32x4 acc[4][4] = {};

    for (int k0 = 0; k0 < K1_; k0 += 32) {
        if (k0 < C1_) {
            const float* up = uf + ((size_t)b * C1_ + k0) * N_ + nb;
            for (int i = 0; i < 8; ++i) {
                int id = i * 256 + t;
                int kkp = id >> 7;           // channel pair 0..15
                int r = id & 127;            // point 0..127
                float v0 = up[(size_t)(2 * kkp) * N_ + r];
                float v1 = up[(size_t)(2 * kkp + 1) * N_ + r];
                As32[r * 16 + kkp] = (uint_t)f2b(v0) | ((uint_t)f2b(v1) << 16);
            }
        } else {
            for (int j = 0; j < 2; ++j) {
                int rbase = wid * 32 + j * 16;
                async16(interp + ((size_t)(row0 + rbase + srow)) * C2_ + (k0 - C1_) + kc * 8,
                        &As[rbase * 32]);
            }
        }
        for (int j = 0; j < 2; ++j) {
            int rbase = wid * 32 + j * 16;
            async16(w1b + ((size_t)(col0 + rbase + srow)) * K1_ + k0 + kc * 8,
                    &Bs[rbase * 32]);
        }
        __syncthreads();

        s16x8 af[4], bfr[4];
        for (int i = 0; i < 4; ++i)
            af[i] = *(const s16x8*)&As[(wm * 64 + i * 16 + l15) * 32 + quad * 8];
        for (int j = 0; j < 4; ++j)
            bfr[j] = *(const s16x8*)&Bs[(wn * 64 + j * 16 + l15) * 32 + quad * 8];
        for (int i = 0; i < 4; ++i)
            for (int j = 0; j < 4; ++j)
                acc[i][j] = __builtin_amdgcn_mfma_f32_16x16x32_bf16(
                    af[i], bfr[j], acc[i][j], 0, 0, 0);
        __syncthreads();
    }

    for (int i = 0; i < 4; ++i)
        for (int j = 0; j < 4; ++j)
            for (int r = 0; r < 4; ++r) {
                int m = row0 + wm * 64 + i * 16 + quad * 4 + r;
                int n = col0 + wn * 64 + j * 16 + l15;
                x1[(size_t)m * H_ + n] = f2b(acc[i][j][r]);
            }
}

// ---------------------------------------------------------------------------
// GEMM2 (plain): C(P,256) = A(P,K) * Bw(256,K)^T, bf16, K param (=256).
// ---------------------------------------------------------------------------
__global__ __launch_bounds__(256) void gemm_bt_k(
    const ushort_t* __restrict__ A, const ushort_t* __restrict__ Bw,
    ushort_t* __restrict__ C, int K) {
    __shared__ ushort_t As[128 * 32];
    __shared__ ushort_t Bs[128 * 32];
    int t = threadIdx.x, lane = t & 63, wid = t >> 6;
    int wm = wid & 1, wn = wid >> 1;
    int row0 = blockIdx.x * 128, col0 = blockIdx.y * 128;
    int quad = lane >> 4, l15 = lane & 15;
    int srow = lane >> 2, kc = lane & 3;

    f32x4 acc[4][4] = {};

    for (int k0 = 0; k0 < K; k0 += 32) {
        for (int j = 0; j < 2; ++j) {
            int rbase = wid * 32 + j * 16;
            async16(A + ((size_t)(row0 + rbase + srow)) * K + k0 + kc * 8,
                    &As[rbase * 32]);
            async16(Bw + ((size_t)(col0 + rbase + srow)) * K + k0 + kc * 8,
                    &Bs[rbase * 32]);
        }
        __syncthreads();

        s16x8 af[4], bfr[4];
        for (int i = 0; i < 4; ++i)
            af[i] = *(const s16x8*)&As[(wm * 64 + i * 16 + l15) * 32 + quad * 8];
        for (int j = 0; j < 4; ++j)
            bfr[j] = *(const s16x8*)&Bs[(wn * 64 + j * 16 + l15) * 32 + quad * 8];
        for (int i = 0; i < 4; ++i)
            for (int j = 0; j < 4; ++j)
                acc[i][j] = __builtin_amdgcn_mfma_f32_16x16x32_bf16(
                    af[i], bfr[j], acc[i][j], 0, 0, 0);
        __syncthreads();
    }

    for (int i = 0; i < 4; ++i)
        for (int j = 0; j < 4; ++j)
            for (int r = 0; r < 4; ++r) {
                int m = row0 + wm * 64 + i * 16 + quad * 4 + r;
                int n = col0 + wn * 64 + j * 16 + l15;
                C[(size_t)m * H_ + n] = f2b(acc[i][j][r]);
            }
}

// ---------------------------------------------------------------------------
__global__ __launch_bounds__(256) void stats_k(
    const ushort_t* __restrict__ x, float* __restrict__ sum, float* __restrict__ sq) {
    int t = threadIdx.x;
    int r0 = blockIdx.x * 256;
    float s = 0.f, q = 0.f;
    for (int r = 0; r < 256; ++r) {
        float v = b2f(x[(size_t)(r0 + r) * 256 + t]);
        s += v; q += v * v;
    }
    atomicAdd(&sum[t], s);
    atomicAdd(&sq[t], q);
}

__global__ __launch_bounds__(256) void coef_k(
    const float* __restrict__ sum, const float* __restrict__ sq,
    const float* __restrict__ g, const float* __restrict__ bt,
    float* __restrict__ a, float* __restrict__ c) {
    int t = threadIdx.x;
    float mean = sum[t] * (1.0f / P_);
    float var  = sq[t] * (1.0f / P_) - mean * mean;
    float ai = g[t] * rsqrtf(var + 1e-5f);
    a[t] = ai;
    c[t] = bt[t] - mean * ai;
}

// BN + ReLU elementwise: x1 (P,256) bf16 -> h1 bf16, one uint4 (8 elems)/thread
__global__ __launch_bounds__(256) void bnrelu_k(
    const uint4* __restrict__ x, const float* __restrict__ a,
    const float* __restrict__ c, uint4* __restrict__ h) {
    size_t i = (size_t)blockIdx.x * 256 + threadIdx.x;   // 2,097,152 uint4s
    uint4 v = x[i];
    int chb = (int)((i * 8) & 255);
    const ushort_t* pv = (const ushort_t*)&v;
    uint4 o; ushort_t* po = (ushort_t*)&o;
    for (int j = 0; j < 8; ++j) {
        float f = b2f(pv[j]);
        f = a[chb + j] * f + c[chb + j];
        po[j] = f2b(fmaxf(f, 0.0f));
    }
    h[i] = o;
}

// BN + ReLU + transpose: x2 (P,256) bf16 -> out (B,256,N) f32, 64x64 tiles
__global__ __launch_bounds__(256) void final_k(
    const ushort_t* __restrict__ x2, const float* __restrict__ a,
    const float* __restrict__ c, float* __restrict__ out) {
    __shared__ float tile[64][65];
    int n0 = blockIdx.x * 64, c0 = blockIdx.y * 64, b = blockIdx.z;
    int t = threadIdx.x;
    {
        int cl = t & 63, pb = (t >> 6) * 16;
        float av = a[c0 + cl], cv = c[c0 + cl];
        for (int i = 0; i < 16; ++i) {
            float v = b2f(x2[((size_t)b * N_ + n0 + pb + i) * H_ + c0 + cl]);
            tile[cl][pb + i] = fmaxf(av * v + cv, 0.0f);
        }
    }
    __syncthreads();
    {
        int nl = t & 63, cb = (t >> 6) * 16;
        for (int i = 0; i < 16; ++i)
            out[((size_t)b * H_ + c0 + cb + i) * N_ + n0 + nl] = tile[cb + i][nl];
    }
}

// ---------------------------------------------------------------------------
extern "C" void kernel_launch(void* const* d_in, const int* in_sizes, int n_in,
                              void* d_out, int out_size, void* d_ws, size_t ws_size,
                              hipStream_t stream) {
    const float* unknown = (const float*)d_in[0];
    const float* known   = (const float*)d_in[1];
    const float* uf      = (const float*)d_in[2];
    const float* kf      = (const float*)d_in[3];
    const float* w1      = (const float*)d_in[4];
    const float* g1      = (const float*)d_in[5];
    const float* b1      = (const float*)d_in[6];
    const float* w2      = (const float*)d_in[7];
    const float* g2      = (const float*)d_in[8];
    const float* b2      = (const float*)d_in[9];
    float* out = (float*)d_out;

    char* ws = (char*)d_ws;
    // [0, 8K): stats — sum1,sq1,sum2,sq2,a1,c1,a2,c2 (8 x 256 f32)
    float* sum1 = (float*)ws;
    float* sq1  = sum1 + 256;
    float* sum2 = sum1 + 512;
    float* sq2  = sum1 + 768;
    float* a1   = sum1 + 1024;
    float* c1   = sum1 + 1280;
    float* a2   = sum1 + 1536;
    float* c2   = sum1 + 1792;
    // [8K, ~520K): converted weights
    ushort_t* w1b = (ushort_t*)(ws + 8192);                        // 384 KB
    ushort_t* w2b = (ushort_t*)(ws + 8192 + (size_t)H_ * K1_ * 2); // 128 KB
    const size_t MB = 1024 * 1024;
    ushort_t* kfT    = (ushort_t*)(ws + 1 * MB);    // 16 MB  [dead after gather_k]
    ushort_t* interp = (ushort_t*)(ws + 17 * MB);   // 64 MB  [dead after gemm1]
    ushort_t* h1     = (ushort_t*)(ws + 17 * MB);   // 32 MB  (over interp lo half)
    ushort_t* x2     = (ushort_t*)(ws + 49 * MB);   // 32 MB  (over interp hi half)
    ushort_t* x1     = (ushort_t*)(ws + 81 * MB);   // 32 MB
    // knn outputs live in the (not-yet-written) x1 region; consumed by gather_k
    // strictly before gemm1 writes x1 (same stream, serialized).
    int4*   idx3 = (int4*)(ws + 81 * MB);           // 1 MB
    float4* wgt3 = (float4*)(ws + 82 * MB);         // 1 MB  -> peak 113 MB

    zero_k<<<8, 256, 0, stream>>>(sum1);
    cvtw_k<<<1024, 256, 0, stream>>>(w1, w2, w1b, w2b);
    tkf_k<<<dim3(16, 8, 16), 256, 0, stream>>>(kf, kfT);
    knn_k<<<2048, 256, 0, stream>>>(unknown, known, idx3, wgt3);
    gather_k<<<2048, 256, 0, stream>>>(idx3, wgt3, kfT, interp);
    gemm1_k<<<dim3(512, 2), 256, 0, stream>>>(uf, interp, w1b, x1);
    stats_k<<<256, 256, 0, stream>>>(x1, sum1, sq1);
    coef_k<<<1, 256, 0, stream>>>(sum1, sq1, g1, b1, a1, c1);
    bnrelu_k<<<8192, 256, 0, stream>>>((const uint4*)x1, a1, c1, (uint4*)h1);
    gemm_bt_k<<<dim3(512, 2), 256, 0, stream>>>(h1, w2b, x2, H_);
    stats_k<<<256, 256, 0, stream>>>(x2, sum2, sq2);
    coef_k<<<1, 256, 0, stream>>>(sum2, sq2, g2, b2, a2, c2);
    final_k<<<dim3(64, 4, 16), 256, 0, stream>>>(x2, a2, c2, out);
}

// Round 5
// 402.457 us; speedup vs baseline: 1.2695x; 1.1147x over previous
//
#include <hip/hip_runtime.h>
#include <stdint.h>

#define B_   16
#define N_   4096
#define M_   1024
#define C1_  256
#define C2_  512
#define H_   256
#define K1_  768      // C1+C2
#define P_   65536    // B*N

typedef unsigned int  uint_t;
typedef unsigned short ushort_t;
typedef __attribute__((ext_vector_type(4))) float f32x4;
typedef __attribute__((ext_vector_type(8))) short s16x8;

__device__ __forceinline__ float b2f(ushort_t u) {
    union { uint_t i; float f; } v; v.i = ((uint_t)u) << 16; return v.f;
}
__device__ __forceinline__ ushort_t f2b(float f) {
    union { float f; uint_t i; } v; v.f = f;
    uint_t x = v.i;
    return (ushort_t)((x + 0x7fffu + ((x >> 16) & 1u)) >> 16);  // RNE
}

__device__ __forceinline__ void async16(const void* g, void* l) {
    __builtin_amdgcn_global_load_lds(
        (const __attribute__((address_space(1))) uint_t*)g,
        (__attribute__((address_space(3))) uint_t*)l, 16, 0, 0);
}

// ---------------------------------------------------------------------------
__global__ __launch_bounds__(256) void zero_k(float* __restrict__ p) {
    p[blockIdx.x * 256 + threadIdx.x] = 0.0f;
}

// ---------------------------------------------------------------------------
// Convert w1 (256x768 f32) and w2 (256x256 f32) to bf16.
// ---------------------------------------------------------------------------
__global__ __launch_bounds__(256) void cvtw_k(
    const float* __restrict__ w1, const float* __restrict__ w2,
    ushort_t* __restrict__ w1b, ushort_t* __restrict__ w2b) {
    int t = blockIdx.x * 256 + threadIdx.x;   // 262144 total
    if (t < H_ * K1_) w1b[t] = f2b(w1[t]);
    else { int u = t - H_ * K1_; w2b[u] = f2b(w2[u]); }
}

// ---------------------------------------------------------------------------
// known_feats (B, 512, 1024) f32 -> kfT (B, 1024, 512) bf16, 64x64 LDS tiles
// ---------------------------------------------------------------------------
__global__ __launch_bounds__(256) void tkf_k(
    const float* __restrict__ in, ushort_t* __restrict__ out) {
    __shared__ ushort_t tile[64][65];
    int m0 = blockIdx.x * 64, c0 = blockIdx.y * 64, b = blockIdx.z;
    int t = threadIdx.x;
    {
        int ml = t & 63, cb = (t >> 6) * 16;
        const float* ip = in + ((size_t)b * C2_ + c0) * M_ + m0;
        for (int i = 0; i < 16; ++i)
            tile[cb + i][ml] = f2b(ip[(size_t)(cb + i) * M_ + ml]);
    }
    __syncthreads();
    {
        int cl = t & 63, mb = (t >> 6) * 16;
        for (int i = 0; i < 16; ++i)
            out[((size_t)b * M_ + m0 + mb + i) * C2_ + c0 + cl] = tile[cl][mb + i];
    }
}

// ---------------------------------------------------------------------------
// 3-NN, 8 threads per point, candidate dim split 8-way INTERLEAVED
// (thread sub scans m = 8*k + sub) so the 8 subs of a point hit 8 distinct
// LDS banks. fp64 ranking, min-index tie-break — output identical.
// ---------------------------------------------------------------------------
__device__ __forceinline__ void ins3d(double d, int m,
                                      double& d0, int& i0, double& d1, int& i1,
                                      double& d2, int& i2) {
    if (d < d2 || (d == d2 && m < i2)) {
        d2 = d; i2 = m;
        if (d2 < d1 || (d2 == d1 && i2 < i1)) { double td = d1; d1 = d2; d2 = td; int ti = i1; i1 = i2; i2 = ti; }
        if (d1 < d0 || (d1 == d0 && i1 < i0)) { double td = d0; d0 = d1; d1 = td; int ti = i0; i0 = i1; i1 = ti; }
    }
}

__global__ __launch_bounds__(256) void knn_k(
    const float* __restrict__ unknown, const float* __restrict__ known,
    int4* __restrict__ idx3, float4* __restrict__ wgt3) {
    __shared__ float kx[M_], ky[M_], kz[M_];
    __shared__ double ksd[M_];
    int b = blockIdx.x >> 7;               // 2048 blocks, 128 per batch
    int n0 = (blockIdx.x & 127) * 32;      // 32 points per block
    int t = threadIdx.x;
    int pl = t >> 3;                       // point-local 0..31
    int sub = t & 7;                       // candidate slice 0..7

    for (int m = t; m < M_; m += 256) {
        float x = known[((size_t)b * M_ + m) * 3 + 0];
        float y = known[((size_t)b * M_ + m) * 3 + 1];
        float z = known[((size_t)b * M_ + m) * 3 + 2];
        kx[m] = x; ky[m] = y; kz[m] = z;
        ksd[m] = (double)x * x + (double)y * y + (double)z * z;
    }
    __syncthreads();

    int n = n0 + pl;
    double qx = (double)unknown[((size_t)b * N_ + n) * 3 + 0];
    double qy = (double)unknown[((size_t)b * N_ + n) * 3 + 1];
    double qz = (double)unknown[((size_t)b * N_ + n) * 3 + 2];
    double qs = qx * qx + qy * qy + qz * qz;

    double D0[2], D1[2], D2[2];
    int    I0[2], I1[2], I2[2];
#pragma unroll
    for (int s = 0; s < 2; ++s) {
        D0[s] = 1e300; D1[s] = 1e300; D2[s] = 1e300;
        I0[s] = 0x7fffffff; I1[s] = 0x7fffffff; I2[s] = 0x7fffffff;
    }

    for (int j = 0; j < 64; ++j) {
#pragma unroll
        for (int s = 0; s < 2; ++s) {
            int m = 8 * (2 * j + s) + sub;   // interleaved: bank = (8k+sub)%32, distinct per sub
            double dot = qx * (double)kx[m] + qy * (double)ky[m] + qz * (double)kz[m];
            double d = qs + ksd[m] - 2.0 * dot;
            ins3d(d, m, D0[s], I0[s], D1[s], I1[s], D2[s], I2[s]);
        }
    }
    // merge stream 1 into 0
    ins3d(D0[1], I0[1], D0[0], I0[0], D1[0], I1[0], D2[0], I2[0]);
    ins3d(D1[1], I1[1], D0[0], I0[0], D1[0], I1[0], D2[0], I2[0]);
    ins3d(D2[1], I2[1], D0[0], I0[0], D1[0], I1[0], D2[0], I2[0]);

    // merge across the 8 subs (lane bits 0..2) — sorted-triple butterfly
#pragma unroll
    for (int off = 1; off < 8; off <<= 1) {
        double e0 = __shfl_xor(D0[0], off), e1 = __shfl_xor(D1[0], off), e2 = __shfl_xor(D2[0], off);
        int    j0 = __shfl_xor(I0[0], off), j1 = __shfl_xor(I1[0], off), j2 = __shfl_xor(I2[0], off);
        ins3d(e0, j0, D0[0], I0[0], D1[0], I1[0], D2[0], I2[0]);
        ins3d(e1, j1, D0[0], I0[0], D1[0], I1[0], D2[0], I2[0]);
        ins3d(e2, j2, D0[0], I0[0], D1[0], I1[0], D2[0], I2[0]);
    }

    if (sub == 0) {
        double w0 = 1.0 / (D0[0] + 1e-8);
        double w1 = 1.0 / (D1[0] + 1e-8);
        double w2 = 1.0 / (D2[0] + 1e-8);
        double inv = 1.0 / (w0 + w1 + w2);
        size_t p = (size_t)b * N_ + n;
        idx3[p] = make_int4(I0[0], I1[0], I2[0], 0);
        wgt3[p] = make_float4((float)(w0 * inv), (float)(w1 * inv), (float)(w2 * inv), 0.f);
    }
}

// ---------------------------------------------------------------------------
// Weighted gather: wave per point, 8 points/wave, idx/wgt prefetch depth 1.
// interp (P, 512) bf16.
// ---------------------------------------------------------------------------
__global__ __launch_bounds__(256) void gather_k(
    const int4* __restrict__ idx3, const float4* __restrict__ wgt3,
    const ushort_t* __restrict__ kfT, ushort_t* __restrict__ interp) {
    int blk = blockIdx.x;             // 2048 blocks
    int b = blk >> 7;                 // 128 blocks per batch
    int n0 = (blk & 127) * 32;
    int lane = threadIdx.x & 63, wid = threadIdx.x >> 6;

    size_t pbase = (size_t)b * N_ + n0 + wid * 8;
    int4 id = idx3[pbase];
    float4 w = wgt3[pbase];
    for (int it = 0; it < 8; ++it) {
        int4 idn; float4 wn;
        if (it < 7) { idn = idx3[pbase + it + 1]; wn = wgt3[pbase + it + 1]; }
        const uint4* r0 = (const uint4*)(kfT + ((size_t)b * M_ + id.x) * C2_);
        const uint4* r1 = (const uint4*)(kfT + ((size_t)b * M_ + id.y) * C2_);
        const uint4* r2 = (const uint4*)(kfT + ((size_t)b * M_ + id.z) * C2_);
        uint4 v0 = r0[lane], v1 = r1[lane], v2 = r2[lane];
        const ushort_t* p0 = (const ushort_t*)&v0;
        const ushort_t* p1 = (const ushort_t*)&v1;
        const ushort_t* p2 = (const ushort_t*)&v2;
        uint4 o; ushort_t* po = (ushort_t*)&o;
        for (int j = 0; j < 8; ++j) {
            float f = w.x * b2f(p0[j]) + w.y * b2f(p1[j]) + w.z * b2f(p2[j]);
            po[j] = f2b(f);
        }
        ((uint4*)(interp + (pbase + it) * C2_))[lane] = o;
        id = idn; w = wn;
    }
}

// ---------------------------------------------------------------------------
// GEMM1: x1(P,256) = [ufT | interp] (P,768) * w1b(256,768)^T, bf16 MFMA.
// K<256: A staged straight from uf f32 (fused transpose+cvt via LDS).
// K>=256: A staged from interp bf16 via global_load_lds (16B).
// ---------------------------------------------------------------------------
__global__ __launch_bounds__(256) void gemm1_k(
    const float* __restrict__ uf, const ushort_t* __restrict__ interp,
    const ushort_t* __restrict__ w1b, ushort_t* __restrict__ x1) {
    __shared__ ushort_t As[128 * 32];
    __shared__ ushort_t Bs[128 * 32];
    int t = threadIdx.x, lane = t & 63, wid = t >> 6;
    int wm = wid & 1, wn = wid >> 1;
    int row0 = blockIdx.x * 128, col0 = blockIdx.y * 128;
    int quad = lane >> 4, l15 = lane & 15;
    int srow = lane >> 2, kc = lane & 3;
    int b = row0 >> 12, nb = row0 & 4095;   // 128 points always within one batch
    uint_t* As32 = (uint_t*)As;

    f32x4 acc[4][4] = {};

    for (int k0 = 0; k0 < K1_; k0 += 32) {
        if (k0 < C1_) {
            const float* up = uf + ((size_t)b * C1_ + k0) * N_ + nb;
            for (int i = 0; i < 8; ++i) {
                int id = i * 256 + t;
                int kkp = id >> 7;           // channel pair 0..15
                int r = id & 127;            // point 0..127
                float v0 = up[(size_t)(2 * kkp) * N_ + r];
                float v1 = up[(size_t)(2 * kkp + 1) * N_ + r];
                As32[r * 16 + kkp] = (uint_t)f2b(v0) | ((uint_t)f2b(v1) << 16);
            }
        } else {
            for (int j = 0; j < 2; ++j) {
                int rbase = wid * 32 + j * 16;
                async16(interp + ((size_t)(row0 + rbase + srow)) * C2_ + (k0 - C1_) + kc * 8,
                        &As[rbase * 32]);
            }
        }
        for (int j = 0; j < 2; ++j) {
            int rbase = wid * 32 + j * 16;
            async16(w1b + ((size_t)(col0 + rbase + srow)) * K1_ + k0 + kc * 8,
                    &Bs[rbase * 32]);
        }
        __syncthreads();

        s16x8 af[4], bfr[4];
        for (int i = 0; i < 4; ++i)
            af[i] = *(const s16x8*)&As[(wm * 64 + i * 16 + l15) * 32 + quad * 8];
        for (int j = 0; j < 4; ++j)
            bfr[j] = *(const s16x8*)&Bs[(wn * 64 + j * 16 + l15) * 32 + quad * 8];
        for (int i = 0; i < 4; ++i)
            for (int j = 0; j < 4; ++j)
                acc[i][j] = __builtin_amdgcn_mfma_f32_16x16x32_bf16(
                    af[i], bfr[j], acc[i][j], 0, 0, 0);
        __syncthreads();
    }

    for (int i = 0; i < 4; ++i)
        for (int j = 0; j < 4; ++j)
            for (int r = 0; r < 4; ++r) {
                int m = row0 + wm * 64 + i * 16 + quad * 4 + r;
                int n = col0 + wn * 64 + j * 16 + l15;
                x1[(size_t)m * H_ + n] = f2b(acc[i][j][r]);
            }
}

// ---------------------------------------------------------------------------
// GEMM2 (plain): C(P,256) = A(P,K) * Bw(256,K)^T, bf16, K param (=256).
// ---------------------------------------------------------------------------
__global__ __launch_bounds__(256) void gemm_bt_k(
    const ushort_t* __restrict__ A, const ushort_t* __restrict__ Bw,
    ushort_t* __restrict__ C, int K) {
    __shared__ ushort_t As[128 * 32];
    __shared__ ushort_t Bs[128 * 32];
    int t = threadIdx.x, lane = t & 63, wid = t >> 6;
    int wm = wid & 1, wn = wid >> 1;
    int row0 = blockIdx.x * 128, col0 = blockIdx.y * 128;
    int quad = lane >> 4, l15 = lane & 15;
    int srow = lane >> 2, kc = lane & 3;

    f32x4 acc[4][4] = {};

    for (int k0 = 0; k0 < K; k0 += 32) {
        for (int j = 0; j < 2; ++j) {
            int rbase = wid * 32 + j * 16;
            async16(A + ((size_t)(row0 + rbase + srow)) * K + k0 + kc * 8,
                    &As[rbase * 32]);
            async16(Bw + ((size_t)(col0 + rbase + srow)) * K + k0 + kc * 8,
                    &Bs[rbase * 32]);
        }
        __syncthreads();

        s16x8 af[4], bfr[4];
        for (int i = 0; i < 4; ++i)
            af[i] = *(const s16x8*)&As[(wm * 64 + i * 16 + l15) * 32 + quad * 8];
        for (int j = 0; j < 4; ++j)
            bfr[j] = *(const s16x8*)&Bs[(wn * 64 + j * 16 + l15) * 32 + quad * 8];
        for (int i = 0; i < 4; ++i)
            for (int j = 0; j < 4; ++j)
                acc[i][j] = __builtin_amdgcn_mfma_f32_16x16x32_bf16(
                    af[i], bfr[j], acc[i][j], 0, 0, 0);
        __syncthreads();
    }

    for (int i = 0; i < 4; ++i)
        for (int j = 0; j < 4; ++j)
            for (int r = 0; r < 4; ++r) {
                int m = row0 + wm * 64 + i * 16 + quad * 4 + r;
                int n = col0 + wn * 64 + j * 16 + l15;
                C[(size_t)m * H_ + n] = f2b(acc[i][j][r]);
            }
}

// ---------------------------------------------------------------------------
__global__ __launch_bounds__(256) void stats_k(
    const ushort_t* __restrict__ x, float* __restrict__ sum, float* __restrict__ sq) {
    int t = threadIdx.x;
    int r0 = blockIdx.x * 256;
    float s = 0.f, q = 0.f;
    for (int r = 0; r < 256; ++r) {
        float v = b2f(x[(size_t)(r0 + r) * 256 + t]);
        s += v; q += v * v;
    }
    atomicAdd(&sum[t], s);
    atomicAdd(&sq[t], q);
}

__global__ __launch_bounds__(256) void coef_k(
    const float* __restrict__ sum, const float* __restrict__ sq,
    const float* __restrict__ g, const float* __restrict__ bt,
    float* __restrict__ a, float* __restrict__ c) {
    int t = threadIdx.x;
    float mean = sum[t] * (1.0f / P_);
    float var  = sq[t] * (1.0f / P_) - mean * mean;
    float ai = g[t] * rsqrtf(var + 1e-5f);
    a[t] = ai;
    c[t] = bt[t] - mean * ai;
}

// BN + ReLU elementwise: x1 (P,256) bf16 -> h1 bf16, one uint4 (8 elems)/thread
__global__ __launch_bounds__(256) void bnrelu_k(
    const uint4* __restrict__ x, const float* __restrict__ a,
    const float* __restrict__ c, uint4* __restrict__ h) {
    size_t i = (size_t)blockIdx.x * 256 + threadIdx.x;   // 2,097,152 uint4s
    uint4 v = x[i];
    int chb = (int)((i * 8) & 255);
    const ushort_t* pv = (const ushort_t*)&v;
    uint4 o; ushort_t* po = (ushort_t*)&o;
    for (int j = 0; j < 8; ++j) {
        float f = b2f(pv[j]);
        f = a[chb + j] * f + c[chb + j];
        po[j] = f2b(fmaxf(f, 0.0f));
    }
    h[i] = o;
}

// BN + ReLU + transpose: x2 (P,256) bf16 -> out (B,256,N) f32, 64x64 tiles
__global__ __launch_bounds__(256) void final_k(
    const ushort_t* __restrict__ x2, const float* __restrict__ a,
    const float* __restrict__ c, float* __restrict__ out) {
    __shared__ float tile[64][65];
    int n0 = blockIdx.x * 64, c0 = blockIdx.y * 64, b = blockIdx.z;
    int t = threadIdx.x;
    {
        int cl = t & 63, pb = (t >> 6) * 16;
        float av = a[c0 + cl], cv = c[c0 + cl];
        for (int i = 0; i < 16; ++i) {
            float v = b2f(x2[((size_t)b * N_ + n0 + pb + i) * H_ + c0 + cl]);
            tile[cl][pb + i] = fmaxf(av * v + cv, 0.0f);
        }
    }
    __syncthreads();
    {
        int nl = t & 63, cb = (t >> 6) * 16;
        for (int i = 0; i < 16; ++i)
            out[((size_t)b * H_ + c0 + cb + i) * N_ + n0 + nl] = tile[cb + i][nl];
    }
}

// ---------------------------------------------------------------------------
extern "C" void kernel_launch(void* const* d_in, const int* in_sizes, int n_in,
                              void* d_out, int out_size, void* d_ws, size_t ws_size,
                              hipStream_t stream) {
    const float* unknown = (const float*)d_in[0];
    const float* known   = (const float*)d_in[1];
    const float* uf      = (const float*)d_in[2];
    const float* kf      = (const float*)d_in[3];
    const float* w1      = (const float*)d_in[4];
    const float* g1      = (const float*)d_in[5];
    const float* b1      = (const float*)d_in[6];
    const float* w2      = (const float*)d_in[7];
    const float* g2      = (const float*)d_in[8];
    const float* b2      = (const float*)d_in[9];
    float* out = (float*)d_out;

    char* ws = (char*)d_ws;
    // [0, 8K): stats — sum1,sq1,sum2,sq2,a1,c1,a2,c2 (8 x 256 f32)
    float* sum1 = (float*)ws;
    float* sq1  = sum1 + 256;
    float* sum2 = sum1 + 512;
    float* sq2  = sum1 + 768;
    float* a1   = sum1 + 1024;
    float* c1   = sum1 + 1280;
    float* a2   = sum1 + 1536;
    float* c2   = sum1 + 1792;
    // [8K, ~520K): converted weights
    ushort_t* w1b = (ushort_t*)(ws + 8192);                        // 384 KB
    ushort_t* w2b = (ushort_t*)(ws + 8192 + (size_t)H_ * K1_ * 2); // 128 KB
    const size_t MB = 1024 * 1024;
    ushort_t* kfT    = (ushort_t*)(ws + 1 * MB);    // 16 MB  [dead after gather_k]
    ushort_t* interp = (ushort_t*)(ws + 17 * MB);   // 64 MB  [dead after gemm1]
    ushort_t* h1     = (ushort_t*)(ws + 17 * MB);   // 32 MB  (over interp lo half)
    ushort_t* x2     = (ushort_t*)(ws + 49 * MB);   // 32 MB  (over interp hi half)
    ushort_t* x1     = (ushort_t*)(ws + 81 * MB);   // 32 MB
    // knn outputs live in the (not-yet-written) x1 region; consumed by gather_k
    // strictly before gemm1 writes x1 (same stream, serialized).
    int4*   idx3 = (int4*)(ws + 81 * MB);           // 1 MB
    float4* wgt3 = (float4*)(ws + 82 * MB);         // 1 MB  -> peak 113 MB

    zero_k<<<8, 256, 0, stream>>>(sum1);
    cvtw_k<<<1024, 256, 0, stream>>>(w1, w2, w1b, w2b);
    tkf_k<<<dim3(16, 8, 16), 256, 0, stream>>>(kf, kfT);
    knn_k<<<2048, 256, 0, stream>>>(unknown, known, idx3, wgt3);
    gather_k<<<2048, 256, 0, stream>>>(idx3, wgt3, kfT, interp);
    gemm1_k<<<dim3(512, 2), 256, 0, stream>>>(uf, interp, w1b, x1);
    stats_k<<<256, 256, 0, stream>>>(x1, sum1, sq1);
    coef_k<<<1, 256, 0, stream>>>(sum1, sq1, g1, b1, a1, c1);
    bnrelu_k<<<8192, 256, 0, stream>>>((const uint4*)x1, a1, c1, (uint4*)h1);
    gemm_bt_k<<<dim3(512, 2), 256, 0, stream>>>(h1, w2b, x2, H_);
    stats_k<<<256, 256, 0, stream>>>(x2, sum2, sq2);
    coef_k<<<1, 256, 0, stream>>>(sum2, sq2, g2, b2, a2, c2);
    final_k<<<dim3(64, 4, 16), 256, 0, stream>>>(x2, a2, c2, out);
}

// Round 6
// 395.574 us; speedup vs baseline: 1.2916x; 1.0174x over previous
//
#include <hip/hip_runtime.h>
#include <stdint.h>

#define B_   16
#define N_   4096
#define M_   1024
#define C1_  256
#define C2_  512
#define H_   256
#define K1_  768      // C1+C2
#define P_   65536    // B*N

typedef unsigned int  uint_t;
typedef unsigned short ushort_t;
typedef __attribute__((ext_vector_type(4))) float f32x4;
typedef __attribute__((ext_vector_type(8))) short s16x8;

__device__ __forceinline__ float b2f(ushort_t u) {
    union { uint_t i; float f; } v; v.i = ((uint_t)u) << 16; return v.f;
}
__device__ __forceinline__ ushort_t f2b(float f) {
    union { float f; uint_t i; } v; v.f = f;
    uint_t x = v.i;
    return (ushort_t)((x + 0x7fffu + ((x >> 16) & 1u)) >> 16);  // RNE
}

__device__ __forceinline__ void async16(const void* g, void* l) {
    __builtin_amdgcn_global_load_lds(
        (const __attribute__((address_space(1))) uint_t*)g,
        (__attribute__((address_space(3))) uint_t*)l, 16, 0, 0);
}

// ---------------------------------------------------------------------------
__global__ __launch_bounds__(256) void zero_k(float* __restrict__ p) {
    p[blockIdx.x * 256 + threadIdx.x] = 0.0f;
}

// ---------------------------------------------------------------------------
// Convert w1 (256x768 f32) and w2 (256x256 f32) to bf16.
// ---------------------------------------------------------------------------
__global__ __launch_bounds__(256) void cvtw_k(
    const float* __restrict__ w1, const float* __restrict__ w2,
    ushort_t* __restrict__ w1b, ushort_t* __restrict__ w2b) {
    int t = blockIdx.x * 256 + threadIdx.x;   // 262144 total
    if (t < H_ * K1_) w1b[t] = f2b(w1[t]);
    else { int u = t - H_ * K1_; w2b[u] = f2b(w2[u]); }
}

// ---------------------------------------------------------------------------
// known_feats (B, 512, 1024) f32 -> kfT (B, 1024, 512) bf16, 64x64 LDS tiles
// ---------------------------------------------------------------------------
__global__ __launch_bounds__(256) void tkf_k(
    const float* __restrict__ in, ushort_t* __restrict__ out) {
    __shared__ ushort_t tile[64][65];
    int m0 = blockIdx.x * 64, c0 = blockIdx.y * 64, b = blockIdx.z;
    int t = threadIdx.x;
    {
        int ml = t & 63, cb = (t >> 6) * 16;
        const float* ip = in + ((size_t)b * C2_ + c0) * M_ + m0;
        for (int i = 0; i < 16; ++i)
            tile[cb + i][ml] = f2b(ip[(size_t)(cb + i) * M_ + ml]);
    }
    __syncthreads();
    {
        int cl = t & 63, mb = (t >> 6) * 16;
        for (int i = 0; i < 16; ++i)
            out[((size_t)b * M_ + m0 + mb + i) * C2_ + c0 + cl] = tile[cl][mb + i];
    }
}

// ---------------------------------------------------------------------------
// 3-NN, 8 threads per point, interleaved candidate split (m = 8k + sub).
// Candidates packed as float4 in LDS -> one ds_read_b128 per candidate;
// ks recomputed in fp64 in-register (same op order as before -> bit-identical
// ranking). min-index tie-break preserved.
// ---------------------------------------------------------------------------
__device__ __forceinline__ void ins3d(double d, int m,
                                      double& d0, int& i0, double& d1, int& i1,
                                      double& d2, int& i2) {
    if (d < d2 || (d == d2 && m < i2)) {
        d2 = d; i2 = m;
        if (d2 < d1 || (d2 == d1 && i2 < i1)) { double td = d1; d1 = d2; d2 = td; int ti = i1; i1 = i2; i2 = ti; }
        if (d1 < d0 || (d1 == d0 && i1 < i0)) { double td = d0; d0 = d1; d1 = td; int ti = i0; i0 = i1; i1 = ti; }
    }
}

__global__ __launch_bounds__(256) void knn_k(
    const float* __restrict__ unknown, const float* __restrict__ known,
    int4* __restrict__ idx3, float4* __restrict__ wgt3) {
    __shared__ float4 kpt[M_];             // (x, y, z, unused) — 16 KB
    int b = blockIdx.x >> 7;               // 2048 blocks, 128 per batch
    int n0 = (blockIdx.x & 127) * 32;      // 32 points per block
    int t = threadIdx.x;
    int pl = t >> 3;                       // point-local 0..31
    int sub = t & 7;                       // candidate slice 0..7

    for (int m = t; m < M_; m += 256) {
        float x = known[((size_t)b * M_ + m) * 3 + 0];
        float y = known[((size_t)b * M_ + m) * 3 + 1];
        float z = known[((size_t)b * M_ + m) * 3 + 2];
        kpt[m] = make_float4(x, y, z, 0.0f);
    }
    __syncthreads();

    int n = n0 + pl;
    double qx = (double)unknown[((size_t)b * N_ + n) * 3 + 0];
    double qy = (double)unknown[((size_t)b * N_ + n) * 3 + 1];
    double qz = (double)unknown[((size_t)b * N_ + n) * 3 + 2];
    double qs = qx * qx + qy * qy + qz * qz;

    double D0[2], D1[2], D2[2];
    int    I0[2], I1[2], I2[2];
#pragma unroll
    for (int s = 0; s < 2; ++s) {
        D0[s] = 1e300; D1[s] = 1e300; D2[s] = 1e300;
        I0[s] = 0x7fffffff; I1[s] = 0x7fffffff; I2[s] = 0x7fffffff;
    }

    for (int j = 0; j < 64; ++j) {
#pragma unroll
        for (int s = 0; s < 2; ++s) {
            int m = 8 * (2 * j + s) + sub;   // interleaved: distinct banks per sub
            float4 kp = kpt[m];
            double X = (double)kp.x, Y = (double)kp.y, Z = (double)kp.z;
            double ks = X * X + Y * Y + Z * Z;          // same order as before
            double dot = qx * X + qy * Y + qz * Z;
            double d = qs + ks - 2.0 * dot;
            ins3d(d, m, D0[s], I0[s], D1[s], I1[s], D2[s], I2[s]);
        }
    }
    // merge stream 1 into 0
    ins3d(D0[1], I0[1], D0[0], I0[0], D1[0], I1[0], D2[0], I2[0]);
    ins3d(D1[1], I1[1], D0[0], I0[0], D1[0], I1[0], D2[0], I2[0]);
    ins3d(D2[1], I2[1], D0[0], I0[0], D1[0], I1[0], D2[0], I2[0]);

    // merge across the 8 subs (lane bits 0..2) — sorted-triple butterfly
#pragma unroll
    for (int off = 1; off < 8; off <<= 1) {
        double e0 = __shfl_xor(D0[0], off), e1 = __shfl_xor(D1[0], off), e2 = __shfl_xor(D2[0], off);
        int    j0 = __shfl_xor(I0[0], off), j1 = __shfl_xor(I1[0], off), j2 = __shfl_xor(I2[0], off);
        ins3d(e0, j0, D0[0], I0[0], D1[0], I1[0], D2[0], I2[0]);
        ins3d(e1, j1, D0[0], I0[0], D1[0], I1[0], D2[0], I2[0]);
        ins3d(e2, j2, D0[0], I0[0], D1[0], I1[0], D2[0], I2[0]);
    }

    if (sub == 0) {
        double w0 = 1.0 / (D0[0] + 1e-8);
        double w1 = 1.0 / (D1[0] + 1e-8);
        double w2 = 1.0 / (D2[0] + 1e-8);
        double inv = 1.0 / (w0 + w1 + w2);
        size_t p = (size_t)b * N_ + n;
        idx3[p] = make_int4(I0[0], I1[0], I2[0], 0);
        wgt3[p] = make_float4((float)(w0 * inv), (float)(w1 * inv), (float)(w2 * inv), 0.f);
    }
}

// ---------------------------------------------------------------------------
// Weighted gather: wave per point, 8 points/wave, idx/wgt prefetch depth 1.
// interp (P, 512) bf16.
// ---------------------------------------------------------------------------
__global__ __launch_bounds__(256) void gather_k(
    const int4* __restrict__ idx3, const float4* __restrict__ wgt3,
    const ushort_t* __restrict__ kfT, ushort_t* __restrict__ interp) {
    int blk = blockIdx.x;             // 2048 blocks
    int b = blk >> 7;                 // 128 blocks per batch
    int n0 = (blk & 127) * 32;
    int lane = threadIdx.x & 63, wid = threadIdx.x >> 6;

    size_t pbase = (size_t)b * N_ + n0 + wid * 8;
    int4 id = idx3[pbase];
    float4 w = wgt3[pbase];
    for (int it = 0; it < 8; ++it) {
        int4 idn; float4 wn;
        if (it < 7) { idn = idx3[pbase + it + 1]; wn = wgt3[pbase + it + 1]; }
        const uint4* r0 = (const uint4*)(kfT + ((size_t)b * M_ + id.x) * C2_);
        const uint4* r1 = (const uint4*)(kfT + ((size_t)b * M_ + id.y) * C2_);
        const uint4* r2 = (const uint4*)(kfT + ((size_t)b * M_ + id.z) * C2_);
        uint4 v0 = r0[lane], v1 = r1[lane], v2 = r2[lane];
        const ushort_t* p0 = (const ushort_t*)&v0;
        const ushort_t* p1 = (const ushort_t*)&v1;
        const ushort_t* p2 = (const ushort_t*)&v2;
        uint4 o; ushort_t* po = (ushort_t*)&o;
        for (int j = 0; j < 8; ++j) {
            float f = w.x * b2f(p0[j]) + w.y * b2f(p1[j]) + w.z * b2f(p2[j]);
            po[j] = f2b(f);
        }
        ((uint4*)(interp + (pbase + it) * C2_))[lane] = o;
        id = idn; w = wn;
    }
}

// ---------------------------------------------------------------------------
// GEMM1: x1(P,256) = [ufT | interp] (P,768) * w1b(256,768)^T, bf16 MFMA.
// K<256: A staged from uf f32 — each thread packs 8 channels of one row and
//        emits one conflict-free ds_write_b128 (64 B lane stride).
// K>=256: A staged from interp bf16 via global_load_lds (16B).
// ---------------------------------------------------------------------------
__global__ __launch_bounds__(256) void gemm1_k(
    const float* __restrict__ uf, const ushort_t* __restrict__ interp,
    const ushort_t* __restrict__ w1b, ushort_t* __restrict__ x1) {
    __shared__ ushort_t As[128 * 32];
    __shared__ ushort_t Bs[128 * 32];
    int t = threadIdx.x, lane = t & 63, wid = t >> 6;
    int wm = wid & 1, wn = wid >> 1;
    int row0 = blockIdx.x * 128, col0 = blockIdx.y * 128;
    int quad = lane >> 4, l15 = lane & 15;
    int srow = lane >> 2, kc = lane & 3;
    int b = row0 >> 12, nb = row0 & 4095;   // 128 points always within one batch

    f32x4 acc[4][4] = {};

    for (int k0 = 0; k0 < K1_; k0 += 32) {
        if (k0 < C1_) {
            const float* up = uf + ((size_t)b * C1_ + k0) * N_ + nb;
#pragma unroll
            for (int i = 0; i < 2; ++i) {
                int id = i * 256 + t;        // 0..511
                int r = id & 127;            // point row
                int c = id >> 7;             // 8-channel chunk 0..3
                float v[8];
#pragma unroll
                for (int j = 0; j < 8; ++j)
                    v[j] = up[(size_t)(c * 8 + j) * N_ + r];
                uint4 pk;
                pk.x = (uint_t)f2b(v[0]) | ((uint_t)f2b(v[1]) << 16);
                pk.y = (uint_t)f2b(v[2]) | ((uint_t)f2b(v[3]) << 16);
                pk.z = (uint_t)f2b(v[4]) | ((uint_t)f2b(v[5]) << 16);
                pk.w = (uint_t)f2b(v[6]) | ((uint_t)f2b(v[7]) << 16);
                *(uint4*)&As[r * 32 + c * 8] = pk;   // byte addr 64r+16c: conflict-free
            }
        } else {
            for (int j = 0; j < 2; ++j) {
                int rbase = wid * 32 + j * 16;
                async16(interp + ((size_t)(row0 + rbase + srow)) * C2_ + (k0 - C1_) + kc * 8,
                        &As[rbase * 32]);
            }
        }
        for (int j = 0; j < 2; ++j) {
            int rbase = wid * 32 + j * 16;
            async16(w1b + ((size_t)(col0 + rbase + srow)) * K1_ + k0 + kc * 8,
                    &Bs[rbase * 32]);
        }
        __syncthreads();

        s16x8 af[4], bfr[4];
        for (int i = 0; i < 4; ++i)
            af[i] = *(const s16x8*)&As[(wm * 64 + i * 16 + l15) * 32 + quad * 8];
        for (int j = 0; j < 4; ++j)
            bfr[j] = *(const s16x8*)&Bs[(wn * 64 + j * 16 + l15) * 32 + quad * 8];
        for (int i = 0; i < 4; ++i)
            for (int j = 0; j < 4; ++j)
                acc[i][j] = __builtin_amdgcn_mfma_f32_16x16x32_bf16(
                    af[i], bfr[j], acc[i][j], 0, 0, 0);
        __syncthreads();
    }

    for (int i = 0; i < 4; ++i)
        for (int j = 0; j < 4; ++j)
            for (int r = 0; r < 4; ++r) {
                int m = row0 + wm * 64 + i * 16 + quad * 4 + r;
                int n = col0 + wn * 64 + j * 16 + l15;
                x1[(size_t)m * H_ + n] = f2b(acc[i][j][r]);
            }
}

// ---------------------------------------------------------------------------
// GEMM2 (plain): C(P,256) = A(P,K) * Bw(256,K)^T, bf16, K param (=256).
// ---------------------------------------------------------------------------
__global__ __launch_bounds__(256) void gemm_bt_k(
    const ushort_t* __restrict__ A, const ushort_t* __restrict__ Bw,
    ushort_t* __restrict__ C, int K) {
    __shared__ ushort_t As[128 * 32];
    __shared__ ushort_t Bs[128 * 32];
    int t = threadIdx.x, lane = t & 63, wid = t >> 6;
    int wm = wid & 1, wn = wid >> 1;
    int row0 = blockIdx.x * 128, col0 = blockIdx.y * 128;
    int quad = lane >> 4, l15 = lane & 15;
    int srow = lane >> 2, kc = lane & 3;

    f32x4 acc[4][4] = {};

    for (int k0 = 0; k0 < K; k0 += 32) {
        for (int j = 0; j < 2; ++j) {
            int rbase = wid * 32 + j * 16;
            async16(A + ((size_t)(row0 + rbase + srow)) * K + k0 + kc * 8,
                    &As[rbase * 32]);
            async16(Bw + ((size_t)(col0 + rbase + srow)) * K + k0 + kc * 8,
                    &Bs[rbase * 32]);
        }
        __syncthreads();

        s16x8 af[4], bfr[4];
        for (int i = 0; i < 4; ++i)
            af[i] = *(const s16x8*)&As[(wm * 64 + i * 16 + l15) * 32 + quad * 8];
        for (int j = 0; j < 4; ++j)
            bfr[j] = *(const s16x8*)&Bs[(wn * 64 + j * 16 + l15) * 32 + quad * 8];
        for (int i = 0; i < 4; ++i)
            for (int j = 0; j < 4; ++j)
                acc[i][j] = __builtin_amdgcn_mfma_f32_16x16x32_bf16(
                    af[i], bfr[j], acc[i][j], 0, 0, 0);
        __syncthreads();
    }

    for (int i = 0; i < 4; ++i)
        for (int j = 0; j < 4; ++j)
            for (int r = 0; r < 4; ++r) {
                int m = row0 + wm * 64 + i * 16 + quad * 4 + r;
                int n = col0 + wn * 64 + j * 16 + l15;
                C[(size_t)m * H_ + n] = f2b(acc[i][j][r]);
            }
}

// ---------------------------------------------------------------------------
__global__ __launch_bounds__(256) void stats_k(
    const ushort_t* __restrict__ x, float* __restrict__ sum, float* __restrict__ sq) {
    int t = threadIdx.x;
    int r0 = blockIdx.x * 256;
    float s = 0.f, q = 0.f;
    for (int r = 0; r < 256; ++r) {
        float v = b2f(x[(size_t)(r0 + r) * 256 + t]);
        s += v; q += v * v;
    }
    atomicAdd(&sum[t], s);
    atomicAdd(&sq[t], q);
}

__global__ __launch_bounds__(256) void coef_k(
    const float* __restrict__ sum, const float* __restrict__ sq,
    const float* __restrict__ g, const float* __restrict__ bt,
    float* __restrict__ a, float* __restrict__ c) {
    int t = threadIdx.x;
    float mean = sum[t] * (1.0f / P_);
    float var  = sq[t] * (1.0f / P_) - mean * mean;
    float ai = g[t] * rsqrtf(var + 1e-5f);
    a[t] = ai;
    c[t] = bt[t] - mean * ai;
}

// BN + ReLU elementwise: x1 (P,256) bf16 -> h1 bf16, one uint4 (8 elems)/thread
__global__ __launch_bounds__(256) void bnrelu_k(
    const uint4* __restrict__ x, const float* __restrict__ a,
    const float* __restrict__ c, uint4* __restrict__ h) {
    size_t i = (size_t)blockIdx.x * 256 + threadIdx.x;   // 2,097,152 uint4s
    uint4 v = x[i];
    int chb = (int)((i * 8) & 255);
    const ushort_t* pv = (const ushort_t*)&v;
    uint4 o; ushort_t* po = (ushort_t*)&o;
    for (int j = 0; j < 8; ++j) {
        float f = b2f(pv[j]);
        f = a[chb + j] * f + c[chb + j];
        po[j] = f2b(fmaxf(f, 0.0f));
    }
    h[i] = o;
}

// BN + ReLU + transpose: x2 (P,256) bf16 -> out (B,256,N) f32, 64x64 tiles
__global__ __launch_bounds__(256) void final_k(
    const ushort_t* __restrict__ x2, const float* __restrict__ a,
    const float* __restrict__ c, float* __restrict__ out) {
    __shared__ float tile[64][65];
    int n0 = blockIdx.x * 64, c0 = blockIdx.y * 64, b = blockIdx.z;
    int t = threadIdx.x;
    {
        int cl = t & 63, pb = (t >> 6) * 16;
        float av = a[c0 + cl], cv = c[c0 + cl];
        for (int i = 0; i < 16; ++i) {
            float v = b2f(x2[((size_t)b * N_ + n0 + pb + i) * H_ + c0 + cl]);
            tile[cl][pb + i] = fmaxf(av * v + cv, 0.0f);
        }
    }
    __syncthreads();
    {
        int nl = t & 63, cb = (t >> 6) * 16;
        for (int i = 0; i < 16; ++i)
            out[((size_t)b * H_ + c0 + cb + i) * N_ + n0 + nl] = tile[cb + i][nl];
    }
}

// ---------------------------------------------------------------------------
extern "C" void kernel_launch(void* const* d_in, const int* in_sizes, int n_in,
                              void* d_out, int out_size, void* d_ws, size_t ws_size,
                              hipStream_t stream) {
    const float* unknown = (const float*)d_in[0];
    const float* known   = (const float*)d_in[1];
    const float* uf      = (const float*)d_in[2];
    const float* kf      = (const float*)d_in[3];
    const float* w1      = (const float*)d_in[4];
    const float* g1      = (const float*)d_in[5];
    const float* b1      = (const float*)d_in[6];
    const float* w2      = (const float*)d_in[7];
    const float* g2      = (const float*)d_in[8];
    const float* b2      = (const float*)d_in[9];
    float* out = (float*)d_out;

    char* ws = (char*)d_ws;
    // [0, 8K): stats — sum1,sq1,sum2,sq2,a1,c1,a2,c2 (8 x 256 f32)
    float* sum1 = (float*)ws;
    float* sq1  = sum1 + 256;
    float* sum2 = sum1 + 512;
    float* sq2  = sum1 + 768;
    float* a1   = sum1 + 1024;
    float* c1   = sum1 + 1280;
    float* a2   = sum1 + 1536;
    float* c2   = sum1 + 1792;
    // [8K, ~520K): converted weights
    ushort_t* w1b = (ushort_t*)(ws + 8192);                        // 384 KB
    ushort_t* w2b = (ushort_t*)(ws + 8192 + (size_t)H_ * K1_ * 2); // 128 KB
    const size_t MB = 1024 * 1024;
    ushort_t* kfT    = (ushort_t*)(ws + 1 * MB);    // 16 MB  [dead after gather_k]
    ushort_t* interp = (ushort_t*)(ws + 17 * MB);   // 64 MB  [dead after gemm1]
    ushort_t* h1     = (ushort_t*)(ws + 17 * MB);   // 32 MB  (over interp lo half)
    ushort_t* x2     = (ushort_t*)(ws + 49 * MB);   // 32 MB  (over interp hi half)
    ushort_t* x1     = (ushort_t*)(ws + 81 * MB);   // 32 MB
    // knn outputs live in the (not-yet-written) x1 region; consumed by gather_k
    // strictly before gemm1 writes x1 (same stream, serialized).
    int4*   idx3 = (int4*)(ws + 81 * MB);           // 1 MB
    float4* wgt3 = (float4*)(ws + 82 * MB);         // 1 MB  -> peak 113 MB

    zero_k<<<8, 256, 0, stream>>>(sum1);
    cvtw_k<<<1024, 256, 0, stream>>>(w1, w2, w1b, w2b);
    tkf_k<<<dim3(16, 8, 16), 256, 0, stream>>>(kf, kfT);
    knn_k<<<2048, 256, 0, stream>>>(unknown, known, idx3, wgt3);
    gather_k<<<2048, 256, 0, stream>>>(idx3, wgt3, kfT, interp);
    gemm1_k<<<dim3(512, 2), 256, 0, stream>>>(uf, interp, w1b, x1);
    stats_k<<<256, 256, 0, stream>>>(x1, sum1, sq1);
    coef_k<<<1, 256, 0, stream>>>(sum1, sq1, g1, b1, a1, c1);
    bnrelu_k<<<8192, 256, 0, stream>>>((const uint4*)x1, a1, c1, (uint4*)h1);
    gemm_bt_k<<<dim3(512, 2), 256, 0, stream>>>(h1, w2b, x2, H_);
    stats_k<<<256, 256, 0, stream>>>(x2, sum2, sq2);
    coef_k<<<1, 256, 0, stream>>>(sum2, sq2, g2, b2, a2, c2);
    final_k<<<dim3(64, 4, 16), 256, 0, stream>>>(x2, a2, c2, out);
}